// Round 1
// baseline (4812.814 us; speedup 1.0000x reference)
//
#include <hip/hip_runtime.h>
#include <math.h>

#define N1  40000
#define NN2 20000
#define NN3 10000
#define EE1 640000
#define EE2 320000
#define EE3 160000
#define JPAD 6912   // 6890 padded to multiple of 256
#define JREAL 6890

// ---------------- small node-transform GEMM: Y[n,co] = X[n,ci] @ W[ci,co]
__global__ void k_matmul(const float* __restrict__ X, const float* __restrict__ W,
                         float* __restrict__ Y, int n, int ci, int co) {
  int idx = blockIdx.x * 256 + threadIdx.x;
  if (idx >= n * co) return;
  int row = idx / co, col = idx - row * co;
  const float* xr = X + (size_t)row * ci;
  float s = 0.f;
  for (int k = 0; k < ci; ++k) s = fmaf(xr[k], W[k * co + col], s);
  Y[idx] = s;
}

// ---------------- per-edge FeaSt attention message + scatter-add
__global__ void k_edge(const int* __restrict__ src, const int* __restrict__ dst,
                       const float* __restrict__ xW, const float* __restrict__ xU,
                       const float* __restrict__ c, float* __restrict__ agg,
                       float* __restrict__ cnt, int E, int fo) {
  int e = blockIdx.x * 256 + threadIdx.x;
  if (e >= E) return;
  int s = src[e], d = dst[e];
  float l0 = xU[s * 4 + 0] - xU[d * 4 + 0] + c[0];
  float l1 = xU[s * 4 + 1] - xU[d * 4 + 1] + c[1];
  float l2 = xU[s * 4 + 2] - xU[d * 4 + 2] + c[2];
  float l3 = xU[s * 4 + 3] - xU[d * 4 + 3] + c[3];
  float mx = fmaxf(fmaxf(l0, l1), fmaxf(l2, l3));
  float e0 = expf(l0 - mx), e1 = expf(l1 - mx), e2 = expf(l2 - mx), e3 = expf(l3 - mx);
  float inv = 1.f / (e0 + e1 + e2 + e3);
  float q0 = e0 * inv, q1 = e1 * inv, q2 = e2 * inv, q3 = e3 * inv;
  const float* m = xW + (size_t)s * 4 * fo;
  float* a = agg + (size_t)d * fo;
  for (int o = 0; o < fo; ++o) {
    float msg = q0 * m[o] + q1 * m[fo + o] + q2 * m[2 * fo + o] + q3 * m[3 * fo + o];
    atomicAdd(a + o, msg);
  }
  atomicAdd(cnt + d, 1.f);
}

// ---------------- self-loop contribution (runs after k_edge; exclusive per node -> no atomics)
__global__ void k_selfloop(const float* __restrict__ xW, const float* __restrict__ c,
                           float* __restrict__ agg, float* __restrict__ cnt, int n, int fo) {
  int idx = blockIdx.x * 256 + threadIdx.x;
  if (idx >= n * fo) return;
  int node = idx / fo, o = idx - node * fo;
  float c0 = c[0], c1 = c[1], c2 = c[2], c3 = c[3];
  float mx = fmaxf(fmaxf(c0, c1), fmaxf(c2, c3));
  float e0 = expf(c0 - mx), e1 = expf(c1 - mx), e2 = expf(c2 - mx), e3 = expf(c3 - mx);
  float inv = 1.f / (e0 + e1 + e2 + e3);
  const float* m = xW + (size_t)node * 4 * fo;
  agg[idx] += (e0 * m[o] + e1 * m[fo + o] + e2 * m[2 * fo + o] + e3 * m[3 * fo + o]) * inv;
  if (o == 0) cnt[node] += 1.f;
}

// ---------------- finalize: out = relu(agg/cnt + b), in place
__global__ void k_finalize(float* __restrict__ agg, const float* __restrict__ cnt,
                           const float* __restrict__ b, int n, int fo) {
  int idx = blockIdx.x * 256 + threadIdx.x;
  if (idx >= n * fo) return;
  int node = idx / fo, o = idx - node * fo;
  agg[idx] = fmaxf(agg[idx] / cnt[node] + b[o], 0.f);
}

// ---------------- graclus-style segment max (values >= 0, out pre-zeroed)
__global__ void k_segmax(const float* __restrict__ xin, const int* __restrict__ cl,
                         float* __restrict__ outp, int n, int f) {
  int idx = blockIdx.x * 256 + threadIdx.x;
  if (idx >= n * f) return;
  int node = idx / f, o = idx - node * f;
  atomicMax((int*)&outp[(size_t)cl[node] * f + o], __float_as_int(xin[idx]));
}

// ---------------- concat: out[n, 0:fa] = a[n], out[n, fa:fa+fb] = b[map[n]]
__global__ void k_cat(const float* __restrict__ a, int fa, const float* __restrict__ b, int fb,
                      const int* __restrict__ map, float* __restrict__ outp, int n) {
  int f = fa + fb;
  int idx = blockIdx.x * 256 + threadIdx.x;
  if (idx >= n * f) return;
  int node = idx / f, o = idx - node * f;
  outp[idx] = (o < fa) ? a[(size_t)node * fa + o] : b[(size_t)map[node] * fb + (o - fa)];
}

// ---------------- pad l2W rows to JPAD (zeros), pad l2b/oW with zeros
__global__ void k_pad(const float* __restrict__ l2W, const float* __restrict__ l2b,
                      const float* __restrict__ oW, float* __restrict__ l2Wp,
                      float* __restrict__ l2bp, float* __restrict__ oWp) {
  int idx = blockIdx.x * 256 + threadIdx.x;
  if (idx >= 256 * JPAD) return;
  int k = idx / JPAD, j = idx - k * JPAD;
  l2Wp[idx] = (j < JREAL) ? l2W[k * JREAL + j] : 0.f;
  if (k == 0) {
    l2bp[j] = (j < JREAL) ? l2b[j] : 0.f;
    oWp[j]  = (j < JREAL) ? oW[j]  : 0.f;
  }
}

// ---------------- fused MLP head: sigmoid(relu(relu(h@l1W+l1b)@l2W+l2b)@oW + ob)
// block = 256 threads = 32 (j) x 8 (rows); 64 rows per block; h1 tile in LDS.
__global__ __launch_bounds__(256) void k_final(
    const float* __restrict__ h, const float* __restrict__ l1W,
    const float* __restrict__ l1b, const float* __restrict__ l2Wp,
    const float* __restrict__ l2bp, const float* __restrict__ oWp,
    const float* __restrict__ obp, float* __restrict__ out) {
  __shared__ float h1s[64][256];  // 64 KB
  const int tid = threadIdx.x;
  const int row0 = blockIdx.x * 64;

  // phase 1: h1[r][tid] = relu(h[r] . l1W[:,tid] + l1b[tid])
  float wcol[32];
#pragma unroll
  for (int k = 0; k < 32; ++k) wcol[k] = l1W[k * 256 + tid];
  const float bt = l1b[tid];
  for (int r = 0; r < 64; ++r) {
    const float* hr = h + (size_t)(row0 + r) * 32;
    float s = bt;
#pragma unroll
    for (int k = 0; k < 32; ++k) s = fmaf(hr[k], wcol[k], s);
    h1s[r][tid] = fmaxf(s, 0.f);
  }
  __syncthreads();

  // phase 2: z[r] += relu(h1[r] . l2W[:,j] + l2b[j]) * oW[j]
  const int tc = tid & 31, tr = tid >> 5;
  float zacc[8];
#pragma unroll
  for (int rr = 0; rr < 8; ++rr) zacc[rr] = 0.f;

  for (int jt = 0; jt < JPAD / 256; ++jt) {  // 27 tiles of 256 cols (8 per thread)
    const int j0 = jt * 256 + tc * 8;
    float acc[8][8];
#pragma unroll
    for (int rr = 0; rr < 8; ++rr)
#pragma unroll
      for (int jj = 0; jj < 8; ++jj) acc[rr][jj] = 0.f;

    for (int k = 0; k < 256; k += 4) {
      float4 wv0[4], wv1[4];
#pragma unroll
      for (int kk = 0; kk < 4; ++kk) {
        const float* wr = l2Wp + (size_t)(k + kk) * JPAD + j0;
        wv0[kk] = *(const float4*)wr;
        wv1[kk] = *(const float4*)(wr + 4);
      }
#pragma unroll
      for (int rr = 0; rr < 8; ++rr) {
        float4 hv = *(const float4*)&h1s[tr * 8 + rr][k];
        float hvv[4] = {hv.x, hv.y, hv.z, hv.w};
#pragma unroll
        for (int kk = 0; kk < 4; ++kk) {
          acc[rr][0] = fmaf(hvv[kk], wv0[kk].x, acc[rr][0]);
          acc[rr][1] = fmaf(hvv[kk], wv0[kk].y, acc[rr][1]);
          acc[rr][2] = fmaf(hvv[kk], wv0[kk].z, acc[rr][2]);
          acc[rr][3] = fmaf(hvv[kk], wv0[kk].w, acc[rr][3]);
          acc[rr][4] = fmaf(hvv[kk], wv1[kk].x, acc[rr][4]);
          acc[rr][5] = fmaf(hvv[kk], wv1[kk].y, acc[rr][5]);
          acc[rr][6] = fmaf(hvv[kk], wv1[kk].z, acc[rr][6]);
          acc[rr][7] = fmaf(hvv[kk], wv1[kk].w, acc[rr][7]);
        }
      }
    }
#pragma unroll
    for (int jj = 0; jj < 8; ++jj) {
      const float lb = l2bp[j0 + jj];
      const float w  = oWp[j0 + jj];
#pragma unroll
      for (int rr = 0; rr < 8; ++rr)
        zacc[rr] += fmaxf(acc[rr][jj] + lb, 0.f) * w;
    }
  }

  // reduce over the 32 j-lanes (same tr)
#pragma unroll
  for (int m = 16; m >= 1; m >>= 1)
#pragma unroll
    for (int rr = 0; rr < 8; ++rr) zacc[rr] += __shfl_xor(zacc[rr], m);

  if (tc == 0) {
    const float ob = obp[0];
#pragma unroll
    for (int rr = 0; rr < 8; ++rr) {
      float z = zacc[rr] + ob;
      out[row0 + tr * 8 + rr] = 1.f / (1.f + expf(-z));
    }
  }
}

// ================= host side =================
static void run_conv(const float* xin, const int* ei, int E, int n, int fi, int fo,
                     const float* W, const float* U, const float* c, const float* b,
                     float* agg_out, float* cnt, float* xW, float* xU, hipStream_t stream) {
  int co = 4 * fo;
  k_matmul<<<(n * co + 255) / 256, 256, 0, stream>>>(xin, W, xW, n, fi, co);
  k_matmul<<<(n * 4 + 255) / 256, 256, 0, stream>>>(xin, U, xU, n, fi, 4);
  k_edge<<<(E + 255) / 256, 256, 0, stream>>>(ei, ei + E, xW, xU, c, agg_out, cnt, E, fo);
  k_selfloop<<<(n * fo + 255) / 256, 256, 0, stream>>>(xW, c, agg_out, cnt, n, fo);
  k_finalize<<<(n * fo + 255) / 256, 256, 0, stream>>>(agg_out, cnt, b, n, fo);
}

extern "C" void kernel_launch(void* const* d_in, const int* in_sizes, int n_in,
                              void* d_out, int out_size, void* d_ws, size_t ws_size,
                              hipStream_t stream) {
  const float* x   = (const float*)d_in[0];
  const int* ei1   = (const int*)d_in[1];
  const int* ei2   = (const int*)d_in[2];
  const int* ei3   = (const int*)d_in[3];
  const int* cl1   = (const int*)d_in[4];
  const int* cl2   = (const int*)d_in[5];
  const float* cW1 = (const float*)d_in[6],  *cU1 = (const float*)d_in[7],
             * cc1 = (const float*)d_in[8],  *cb1 = (const float*)d_in[9];
  const float* cW2 = (const float*)d_in[10], *cU2 = (const float*)d_in[11],
             * cc2 = (const float*)d_in[12], *cb2 = (const float*)d_in[13];
  const float* cW3 = (const float*)d_in[14], *cU3 = (const float*)d_in[15],
             * cc3 = (const float*)d_in[16], *cb3 = (const float*)d_in[17];
  const float* cW4 = (const float*)d_in[18], *cU4 = (const float*)d_in[19],
             * cc4 = (const float*)d_in[20], *cb4 = (const float*)d_in[21];
  const float* cW5 = (const float*)d_in[22], *cU5 = (const float*)d_in[23],
             * cc5 = (const float*)d_in[24], *cb5 = (const float*)d_in[25];
  const float* l1W = (const float*)d_in[26], *l1b = (const float*)d_in[27];
  const float* l2W = (const float*)d_in[28], *l2b = (const float*)d_in[29];
  const float* oW  = (const float*)d_in[30], *ob  = (const float*)d_in[31];

  float* ws   = (float*)d_ws;
  float* x1   = ws + 0;        // N1*16
  float* x2   = ws + 640000;   // NN2*32
  float* x5   = ws + 1280000;  // NN2*16
  float* x2p  = ws + 1600000;  // NN2*16
  float* x3p  = ws + 1920000;  // NN3*32
  float* x3a  = ws + 2240000;  // NN3*64
  float* x3b  = ws + 2880000;  // NN3*32
  float* cnt1 = ws + 3200000;  // N1
  float* cnt2 = ws + 3240000;  // NN2
  float* cnt3 = ws + 3260000;  // NN3
  float* cnt4 = ws + 3270000;  // NN3
  float* cnt5 = ws + 3280000;  // NN2
  // --- end of zeroed region (3,300,000 floats) ---
  float* h    = ws + 3300000;  // N1*32   (fully overwritten)
  float* xcat = ws + 4580000;  // NN2*64  (fully overwritten)
  float* l2Wp = ws + 5860000;  // 256*JPAD (fully overwritten)
  float* l2bp = ws + 7629472;  // JPAD
  float* oWp  = ws + 7636384;  // JPAD
  float* xW   = ws + 7643296;  // up to 2,560,000 (fully overwritten per conv)
  float* xU   = ws + 10203296; // up to 160,000
  // total = 10,363,296 floats = 41.5 MB

  hipMemsetAsync(ws, 0, 3300000 * sizeof(float), stream);
  k_pad<<<(256 * JPAD + 255) / 256, 256, 0, stream>>>(l2W, l2b, oW, l2Wp, l2bp, oWp);

  // conv1: x [N1,5] -> x1 [N1,16]
  run_conv(x, ei1, EE1, N1, 5, 16, cW1, cU1, cc1, cb1, x1, cnt1, xW, xU, stream);
  // pool1
  k_segmax<<<(N1 * 16 + 255) / 256, 256, 0, stream>>>(x1, cl1, x2p, N1, 16);
  // conv2: x2p [NN2,16] -> x2 [NN2,32]
  run_conv(x2p, ei2, EE2, NN2, 16, 32, cW2, cU2, cc2, cb2, x2, cnt2, xW, xU, stream);
  // pool2
  k_segmax<<<(NN2 * 32 + 255) / 256, 256, 0, stream>>>(x2, cl2, x3p, NN2, 32);
  // conv3: x3p [NN3,32] -> x3a [NN3,64]
  run_conv(x3p, ei3, EE3, NN3, 32, 64, cW3, cU3, cc3, cb3, x3a, cnt3, xW, xU, stream);
  // conv4: x3a [NN3,64] -> x3b [NN3,32]
  run_conv(x3a, ei3, EE3, NN3, 64, 32, cW4, cU4, cc4, cb4, x3b, cnt4, xW, xU, stream);
  // unpool + skip: xcat [NN2,64]
  k_cat<<<(NN2 * 64 + 255) / 256, 256, 0, stream>>>(x2, 32, x3b, 32, cl2, xcat, NN2);
  // conv5: xcat [NN2,64] -> x5 [NN2,16]
  run_conv(xcat, ei2, EE2, NN2, 64, 16, cW5, cU5, cc5, cb5, x5, cnt5, xW, xU, stream);
  // h = concat(x1, x5[cluster1]) [N1,32]
  k_cat<<<(N1 * 32 + 255) / 256, 256, 0, stream>>>(x1, 16, x5, 16, cl1, h, N1);
  // fused MLP head -> out
  k_final<<<N1 / 64, 256, 0, stream>>>(h, l1W, l1b, l2Wp, l2bp, oWp, ob, (float*)d_out);
}

// Round 2
// 2824.134 us; speedup vs baseline: 1.7042x; 1.7042x over previous
//
#include <hip/hip_runtime.h>
#include <math.h>

#define N1  40000
#define NN2 20000
#define NN3 10000
#define EE1 640000
#define EE2 320000
#define EE3 160000
#define JPAD 6912   // 6890 padded to 432 tiles of 16
#define JREAL 6890
#define NTILE 432   // JPAD/16

typedef __attribute__((ext_vector_type(8))) short short8;
typedef __attribute__((ext_vector_type(4))) float f32x4;

__device__ inline unsigned short f2bf(float f) {
  unsigned u = __float_as_uint(f);
  u += 0x7FFF + ((u >> 16) & 1);   // round-to-nearest-even
  return (unsigned short)(u >> 16);
}

// ---------------- small node-transform GEMM: Y[n,co] = X[n,ci] @ W[ci,co]
__global__ void k_matmul(const float* __restrict__ X, const float* __restrict__ W,
                         float* __restrict__ Y, int n, int ci, int co) {
  int idx = blockIdx.x * 256 + threadIdx.x;
  if (idx >= n * co) return;
  int row = idx / co, col = idx - row * co;
  const float* xr = X + (size_t)row * ci;
  float s = 0.f;
  for (int k = 0; k < ci; ++k) s = fmaf(xr[k], W[k * co + col], s);
  Y[idx] = s;
}

// ---------------- per-edge FeaSt attention message + scatter-add
__global__ void k_edge(const int* __restrict__ src, const int* __restrict__ dst,
                       const float* __restrict__ xW, const float* __restrict__ xU,
                       const float* __restrict__ c, float* __restrict__ agg,
                       float* __restrict__ cnt, int E, int fo) {
  int e = blockIdx.x * 256 + threadIdx.x;
  if (e >= E) return;
  int s = src[e], d = dst[e];
  float l0 = xU[s * 4 + 0] - xU[d * 4 + 0] + c[0];
  float l1 = xU[s * 4 + 1] - xU[d * 4 + 1] + c[1];
  float l2 = xU[s * 4 + 2] - xU[d * 4 + 2] + c[2];
  float l3 = xU[s * 4 + 3] - xU[d * 4 + 3] + c[3];
  float mx = fmaxf(fmaxf(l0, l1), fmaxf(l2, l3));
  float e0 = expf(l0 - mx), e1 = expf(l1 - mx), e2 = expf(l2 - mx), e3 = expf(l3 - mx);
  float inv = 1.f / (e0 + e1 + e2 + e3);
  float q0 = e0 * inv, q1 = e1 * inv, q2 = e2 * inv, q3 = e3 * inv;
  const float* m = xW + (size_t)s * 4 * fo;
  float* a = agg + (size_t)d * fo;
  for (int o = 0; o < fo; ++o) {
    float msg = q0 * m[o] + q1 * m[fo + o] + q2 * m[2 * fo + o] + q3 * m[3 * fo + o];
    atomicAdd(a + o, msg);
  }
  atomicAdd(cnt + d, 1.f);
}

// ---------------- self-loop contribution (after k_edge; exclusive per node)
__global__ void k_selfloop(const float* __restrict__ xW, const float* __restrict__ c,
                           float* __restrict__ agg, float* __restrict__ cnt, int n, int fo) {
  int idx = blockIdx.x * 256 + threadIdx.x;
  if (idx >= n * fo) return;
  int node = idx / fo, o = idx - node * fo;
  float c0 = c[0], c1 = c[1], c2 = c[2], c3 = c[3];
  float mx = fmaxf(fmaxf(c0, c1), fmaxf(c2, c3));
  float e0 = expf(c0 - mx), e1 = expf(c1 - mx), e2 = expf(c2 - mx), e3 = expf(c3 - mx);
  float inv = 1.f / (e0 + e1 + e2 + e3);
  const float* m = xW + (size_t)node * 4 * fo;
  agg[idx] += (e0 * m[o] + e1 * m[fo + o] + e2 * m[2 * fo + o] + e3 * m[3 * fo + o]) * inv;
  if (o == 0) cnt[node] += 1.f;
}

// ---------------- finalize: out = relu(agg/cnt + b), in place
__global__ void k_finalize(float* __restrict__ agg, const float* __restrict__ cnt,
                           const float* __restrict__ b, int n, int fo) {
  int idx = blockIdx.x * 256 + threadIdx.x;
  if (idx >= n * fo) return;
  int node = idx / fo, o = idx - node * fo;
  agg[idx] = fmaxf(agg[idx] / cnt[node] + b[o], 0.f);
}

// ---------------- graclus-style segment max (values >= 0, out pre-zeroed)
__global__ void k_segmax(const float* __restrict__ xin, const int* __restrict__ cl,
                         float* __restrict__ outp, int n, int f) {
  int idx = blockIdx.x * 256 + threadIdx.x;
  if (idx >= n * f) return;
  int node = idx / f, o = idx - node * f;
  atomicMax((int*)&outp[(size_t)cl[node] * f + o], __float_as_int(xin[idx]));
}

// ---------------- concat: out[n, 0:fa] = a[n], out[n, fa:fa+fb] = b[map[n]]
__global__ void k_cat(const float* __restrict__ a, int fa, const float* __restrict__ b, int fb,
                      const int* __restrict__ map, float* __restrict__ outp, int n) {
  int f = fa + fb;
  int idx = blockIdx.x * 256 + threadIdx.x;
  if (idx >= n * f) return;
  int node = idx / f, o = idx - node * f;
  outp[idx] = (o < fa) ? a[(size_t)node * fa + o] : b[(size_t)map[node] * fb + (o - fa)];
}

// ---------------- pad l2b / oW to JPAD with zeros
__global__ void k_padvec(const float* __restrict__ l2b, const float* __restrict__ oW,
                         float* __restrict__ l2bp, float* __restrict__ oWp) {
  int j = blockIdx.x * 256 + threadIdx.x;
  if (j >= JPAD) return;
  l2bp[j] = (j < JREAL) ? l2b[j] : 0.f;
  oWp[j]  = (j < JREAL) ? oW[j]  : 0.f;
}

// ---------------- pack l2W [256][6890] fp32 -> bf16 B-fragments
// layout: Bp[(t*8 + ks)*64 + lane][i] = l2W[ks*32 + (lane>>4)*8 + i][t*16 + (lane&15)]
__global__ void k_packB(const float* __restrict__ l2W, short8* __restrict__ Bp) {
  int idx = blockIdx.x * 256 + threadIdx.x;
  if (idx >= NTILE * 8 * 64) return;
  int l = idx & 63, ks = (idx >> 6) & 7, t = idx >> 9;
  int j = t * 16 + (l & 15);
  int kb = ks * 32 + ((l >> 4) << 3);
  short8 v;
#pragma unroll
  for (int i = 0; i < 8; ++i) {
    float f = (j < JREAL) ? l2W[(size_t)(kb + i) * JREAL + j] : 0.f;
    v[i] = (short)f2bf(f);
  }
  Bp[idx] = v;
}

// ---------------- fused MLP head with bf16 MFMA for the l2 GEMM
// sigmoid(relu(relu(h@l1W+l1b)@l2W+l2b)@oW + ob)
// block = 256 (4 waves); 64 rows/block; each wave: all 64 rows x 1/4 of N=6912.
__global__ __launch_bounds__(256, 2) void k_final(
    const float* __restrict__ h, const float* __restrict__ l1W,
    const float* __restrict__ l1b, const short8* __restrict__ Bp,
    const float* __restrict__ l2bp, const float* __restrict__ oWp,
    const float* __restrict__ obp, float* __restrict__ out) {
  __shared__ float h1s[64][256];  // 64 KB
  const int tid = threadIdx.x;
  const int row0 = blockIdx.x * 64;

  // phase 1: h1[r][tid] = relu(h[r] . l1W[:,tid] + l1b[tid])  (fp32 VALU)
  {
    float wcol[32];
#pragma unroll
    for (int k = 0; k < 32; ++k) wcol[k] = l1W[k * 256 + tid];
    const float bt = l1b[tid];
    for (int r = 0; r < 64; ++r) {
      const float* hr = h + (size_t)(row0 + r) * 32;
      float s = bt;
#pragma unroll
      for (int k = 0; k < 32; ++k) s = fmaf(hr[k], wcol[k], s);
      h1s[r][tid] = fmaxf(s, 0.f);
    }
  }
  __syncthreads();

  const int w  = tid >> 6;      // wave id 0..3
  const int l  = tid & 63;      // lane
  const int lm = l & 15, lh = l >> 4;

  // A fragments: 64 rows x K=256 in registers (bf16), mapping mirrors k_packB
  short8 af[4][8];
#pragma unroll
  for (int rb = 0; rb < 4; ++rb)
#pragma unroll
    for (int ks = 0; ks < 8; ++ks) {
      const float* src = &h1s[rb * 16 + lm][ks * 32 + lh * 8];
      short8 a;
#pragma unroll
      for (int i = 0; i < 8; ++i) a[i] = (short)f2bf(src[i]);
      af[rb][ks] = a;
    }
  __syncthreads();  // h1s reads done; LDS will be reused as zred

  float zp[4][4];
#pragma unroll
  for (int rb = 0; rb < 4; ++rb)
#pragma unroll
    for (int r = 0; r < 4; ++r) zp[rb][r] = 0.f;

  const int t0 = w * (NTILE / 4);
  for (int tt = 0; tt < NTILE / 4; ++tt) {
    const int t = t0 + tt;
    const short8* bp = Bp + (size_t)t * 512 + l;
    short8 bfr[8];
#pragma unroll
    for (int ks = 0; ks < 8; ++ks) bfr[ks] = bp[ks * 64];

    f32x4 acc[4];
#pragma unroll
    for (int rb = 0; rb < 4; ++rb) acc[rb] = (f32x4){0.f, 0.f, 0.f, 0.f};

#pragma unroll
    for (int ks = 0; ks < 8; ++ks)
#pragma unroll
      for (int rb = 0; rb < 4; ++rb)
        acc[rb] = __builtin_amdgcn_mfma_f32_16x16x32_bf16(af[rb][ks], bfr[ks], acc[rb], 0, 0, 0);

    // epilogue: z += relu(acc + l2b[j]) * oW[j]; this lane's col j = t*16+lm
    const int j = t * 16 + lm;
    const float lb = l2bp[j];
    const float ow = oWp[j];
#pragma unroll
    for (int rb = 0; rb < 4; ++rb)
#pragma unroll
      for (int r = 0; r < 4; ++r)
        zp[rb][r] += fmaxf(acc[rb][r] + lb, 0.f) * ow;
  }

  // reduce across the 16 column-lanes
#pragma unroll
  for (int m = 1; m < 16; m <<= 1)
#pragma unroll
    for (int rb = 0; rb < 4; ++rb)
#pragma unroll
      for (int r = 0; r < 4; ++r)
        zp[rb][r] += __shfl_xor(zp[rb][r], m);

  // cross-wave reduce via LDS (reuse h1s storage)
  float* zred = &h1s[0][0];  // [4][64]
  if (lm == 0) {
#pragma unroll
    for (int rb = 0; rb < 4; ++rb)
#pragma unroll
      for (int r = 0; r < 4; ++r)
        zred[w * 64 + rb * 16 + lh * 4 + r] = zp[rb][r];
  }
  __syncthreads();
  if (tid < 64) {
    float z = zred[tid] + zred[64 + tid] + zred[128 + tid] + zred[192 + tid] + obp[0];
    out[row0 + tid] = 1.f / (1.f + expf(-z));
  }
}

// ================= host side =================
static void run_conv(const float* xin, const int* ei, int E, int n, int fi, int fo,
                     const float* W, const float* U, const float* c, const float* b,
                     float* agg_out, float* cnt, float* xW, float* xU, hipStream_t stream) {
  int co = 4 * fo;
  k_matmul<<<(n * co + 255) / 256, 256, 0, stream>>>(xin, W, xW, n, fi, co);
  k_matmul<<<(n * 4 + 255) / 256, 256, 0, stream>>>(xin, U, xU, n, fi, 4);
  k_edge<<<(E + 255) / 256, 256, 0, stream>>>(ei, ei + E, xW, xU, c, agg_out, cnt, E, fo);
  k_selfloop<<<(n * fo + 255) / 256, 256, 0, stream>>>(xW, c, agg_out, cnt, n, fo);
  k_finalize<<<(n * fo + 255) / 256, 256, 0, stream>>>(agg_out, cnt, b, n, fo);
}

extern "C" void kernel_launch(void* const* d_in, const int* in_sizes, int n_in,
                              void* d_out, int out_size, void* d_ws, size_t ws_size,
                              hipStream_t stream) {
  const float* x   = (const float*)d_in[0];
  const int* ei1   = (const int*)d_in[1];
  const int* ei2   = (const int*)d_in[2];
  const int* ei3   = (const int*)d_in[3];
  const int* cl1   = (const int*)d_in[4];
  const int* cl2   = (const int*)d_in[5];
  const float* cW1 = (const float*)d_in[6],  *cU1 = (const float*)d_in[7],
             * cc1 = (const float*)d_in[8],  *cb1 = (const float*)d_in[9];
  const float* cW2 = (const float*)d_in[10], *cU2 = (const float*)d_in[11],
             * cc2 = (const float*)d_in[12], *cb2 = (const float*)d_in[13];
  const float* cW3 = (const float*)d_in[14], *cU3 = (const float*)d_in[15],
             * cc3 = (const float*)d_in[16], *cb3 = (const float*)d_in[17];
  const float* cW4 = (const float*)d_in[18], *cU4 = (const float*)d_in[19],
             * cc4 = (const float*)d_in[20], *cb4 = (const float*)d_in[21];
  const float* cW5 = (const float*)d_in[22], *cU5 = (const float*)d_in[23],
             * cc5 = (const float*)d_in[24], *cb5 = (const float*)d_in[25];
  const float* l1W = (const float*)d_in[26], *l1b = (const float*)d_in[27];
  const float* l2W = (const float*)d_in[28], *l2b = (const float*)d_in[29];
  const float* oW  = (const float*)d_in[30], *ob  = (const float*)d_in[31];

  float* ws   = (float*)d_ws;
  float* x1   = ws + 0;        // N1*16
  float* x2   = ws + 640000;   // NN2*32
  float* x5   = ws + 1280000;  // NN2*16
  float* x2p  = ws + 1600000;  // NN2*16
  float* x3p  = ws + 1920000;  // NN3*32
  float* x3a  = ws + 2240000;  // NN3*64
  float* x3b  = ws + 2880000;  // NN3*32
  float* cnt1 = ws + 3200000;  // N1
  float* cnt2 = ws + 3240000;  // NN2
  float* cnt3 = ws + 3260000;  // NN3
  float* cnt4 = ws + 3270000;  // NN3
  float* cnt5 = ws + 3280000;  // NN2
  // --- end of zeroed region (3,300,000 floats) ---
  float* h    = ws + 3300000;  // N1*32   (fully overwritten)
  float* xcat = ws + 4580000;  // NN2*64  (fully overwritten)
  short8* Bp  = (short8*)(ws + 5860000);  // 432*8*64 frags = 884,736 f32 slots
  float* l2bp = ws + 6744736;  // JPAD
  float* oWp  = ws + 6751648;  // JPAD
  float* xW   = ws + 6758560;  // up to 2,560,000 (overwritten per conv)
  float* xU   = ws + 9318560;  // up to 160,000
  // total = 9,478,560 floats = 37.9 MB

  hipMemsetAsync(ws, 0, 3300000 * sizeof(float), stream);
  k_padvec<<<(JPAD + 255) / 256, 256, 0, stream>>>(l2b, oW, l2bp, oWp);
  k_packB<<<(NTILE * 8 * 64 + 255) / 256, 256, 0, stream>>>(l2W, Bp);

  // conv1: x [N1,5] -> x1 [N1,16]
  run_conv(x, ei1, EE1, N1, 5, 16, cW1, cU1, cc1, cb1, x1, cnt1, xW, xU, stream);
  // pool1
  k_segmax<<<(N1 * 16 + 255) / 256, 256, 0, stream>>>(x1, cl1, x2p, N1, 16);
  // conv2: x2p [NN2,16] -> x2 [NN2,32]
  run_conv(x2p, ei2, EE2, NN2, 16, 32, cW2, cU2, cc2, cb2, x2, cnt2, xW, xU, stream);
  // pool2
  k_segmax<<<(NN2 * 32 + 255) / 256, 256, 0, stream>>>(x2, cl2, x3p, NN2, 32);
  // conv3: x3p [NN3,32] -> x3a [NN3,64]
  run_conv(x3p, ei3, EE3, NN3, 32, 64, cW3, cU3, cc3, cb3, x3a, cnt3, xW, xU, stream);
  // conv4: x3a [NN3,64] -> x3b [NN3,32]
  run_conv(x3a, ei3, EE3, NN3, 64, 32, cW4, cU4, cc4, cb4, x3b, cnt4, xW, xU, stream);
  // unpool + skip: xcat [NN2,64]
  k_cat<<<(NN2 * 64 + 255) / 256, 256, 0, stream>>>(x2, 32, x3b, 32, cl2, xcat, NN2);
  // conv5: xcat [NN2,64] -> x5 [NN2,16]
  run_conv(xcat, ei2, EE2, NN2, 64, 16, cW5, cU5, cc5, cb5, x5, cnt5, xW, xU, stream);
  // h = concat(x1, x5[cluster1]) [N1,32]
  k_cat<<<(N1 * 32 + 255) / 256, 256, 0, stream>>>(x1, 16, x5, 16, cl1, h, N1);
  // fused MLP head -> out
  k_final<<<N1 / 64, 256, 0, stream>>>(h, l1W, l1b, Bp, l2bp, oWp, ob, (float*)d_out);
}

// Round 3
// 827.984 us; speedup vs baseline: 5.8127x; 3.4109x over previous
//
#include <hip/hip_runtime.h>
#include <math.h>

#define N1  40000
#define NN2 20000
#define NN3 10000
#define EE1 640000
#define EE2 320000
#define EE3 160000
#define JPAD 6912   // 6890 padded to 432 tiles of 16
#define JREAL 6890
#define NTILE 432   // JPAD/16

typedef __attribute__((ext_vector_type(8))) short short8;
typedef __attribute__((ext_vector_type(4))) float f32x4;

__device__ inline unsigned short f2bf(float f) {
  unsigned u = __float_as_uint(f);
  u += 0x7FFF + ((u >> 16) & 1);   // round-to-nearest-even
  return (unsigned short)(u >> 16);
}

// ---------------- small node-transform GEMM: Y[n,co] = X[n,ci] @ W[ci,co]
__global__ void k_matmul(const float* __restrict__ X, const float* __restrict__ W,
                         float* __restrict__ Y, int n, int ci, int co) {
  int idx = blockIdx.x * 256 + threadIdx.x;
  if (idx >= n * co) return;
  int row = idx / co, col = idx - row * co;
  const float* xr = X + (size_t)row * ci;
  float s = 0.f;
  for (int k = 0; k < ci; ++k) s = fmaf(xr[k], W[k * co + col], s);
  Y[idx] = s;
}

// ---------------- CSR build: histogram of dst
__global__ void k_hist(const int* __restrict__ dst, int* __restrict__ deg, int E) {
  int e = blockIdx.x * 256 + threadIdx.x;
  if (e >= E) return;
  atomicAdd(&deg[dst[e]], 1);
}

// ---------------- CSR build: exclusive scan (single 1024-thread workgroup)
__global__ __launch_bounds__(1024) void k_scan(const int* __restrict__ deg,
                                               int* __restrict__ rp, int n) {
  __shared__ int ssum[1024];
  const int tid = threadIdx.x;
  const int per = (n + 1023) >> 10;
  const int lo = tid * per, hi = min(lo + per, n);
  int s = 0;
  for (int i = lo; i < hi; ++i) s += deg[i];
  ssum[tid] = s;
  __syncthreads();
  for (int off = 1; off < 1024; off <<= 1) {
    int v = (tid >= off) ? ssum[tid - off] : 0;
    __syncthreads();
    ssum[tid] += v;
    __syncthreads();
  }
  int carry = (tid == 0) ? 0 : ssum[tid - 1];
  for (int i = lo; i < hi; ++i) { rp[i] = carry; carry += deg[i]; }
  if (tid == 1023) rp[n] = carry;
}

// ---------------- CSR build: scatter src ids into dst-sorted order
__global__ void k_scatter(const int* __restrict__ src, const int* __restrict__ dst,
                          const int* __restrict__ rp, int* __restrict__ cur,
                          int* __restrict__ ss, int E) {
  int e = blockIdx.x * 256 + threadIdx.x;
  if (e >= E) return;
  int d = dst[e];
  int pos = rp[d] + atomicAdd(&cur[d], 1);
  ss[pos] = src[e];
}

// ---------------- fused FeaSt aggregation: per (dst node, out feature)
// out[d][o] = relu( (sum_e q_e . xW[s_e][:,o] + q_self . xW[d][:,o]) / (deg+1) + b[o] )
__global__ void k_attagg(const int* __restrict__ rp, const int* __restrict__ ss,
                         const float* __restrict__ xW, const float* __restrict__ xU,
                         const float* __restrict__ c, const float* __restrict__ b,
                         float* __restrict__ outp, int n, int fo) {
  int idx = blockIdx.x * 256 + threadIdx.x;
  if (idx >= n * fo) return;
  int d = idx / fo, o = idx - d * fo;
  const float c0 = c[0], c1 = c[1], c2 = c[2], c3 = c[3];
  const float4 xd = *(const float4*)&xU[(size_t)d * 4];
  const int e0 = rp[d], e1 = rp[d + 1];
  float acc = 0.f;
  for (int e = e0; e < e1; ++e) {
    int s = ss[e];
    float4 xs = *(const float4*)&xU[(size_t)s * 4];
    float l0 = xs.x - xd.x + c0, l1 = xs.y - xd.y + c1;
    float l2 = xs.z - xd.z + c2, l3 = xs.w - xd.w + c3;
    float mx = fmaxf(fmaxf(l0, l1), fmaxf(l2, l3));
    float q0 = __expf(l0 - mx), q1 = __expf(l1 - mx);
    float q2 = __expf(l2 - mx), q3 = __expf(l3 - mx);
    float inv = 1.f / (q0 + q1 + q2 + q3);
    const float* m = xW + (size_t)s * 4 * fo + o;
    acc += (q0 * m[0] + q1 * m[fo] + q2 * m[2 * fo] + q3 * m[3 * fo]) * inv;
  }
  // self-loop: q = softmax(c)
  {
    float mx = fmaxf(fmaxf(c0, c1), fmaxf(c2, c3));
    float q0 = __expf(c0 - mx), q1 = __expf(c1 - mx);
    float q2 = __expf(c2 - mx), q3 = __expf(c3 - mx);
    float inv = 1.f / (q0 + q1 + q2 + q3);
    const float* m = xW + (size_t)d * 4 * fo + o;
    acc += (q0 * m[0] + q1 * m[fo] + q2 * m[2 * fo] + q3 * m[3 * fo]) * inv;
  }
  outp[idx] = fmaxf(acc / (float)(e1 - e0 + 1) + b[o], 0.f);
}

// ---------------- graclus-style segment max (values >= 0, out pre-zeroed)
__global__ void k_segmax(const float* __restrict__ xin, const int* __restrict__ cl,
                         float* __restrict__ outp, int n, int f) {
  int idx = blockIdx.x * 256 + threadIdx.x;
  if (idx >= n * f) return;
  int node = idx / f, o = idx - node * f;
  atomicMax((int*)&outp[(size_t)cl[node] * f + o], __float_as_int(xin[idx]));
}

// ---------------- concat: out[n, 0:fa] = a[n], out[n, fa:fa+fb] = b[map[n]]
__global__ void k_cat(const float* __restrict__ a, int fa, const float* __restrict__ b, int fb,
                      const int* __restrict__ map, float* __restrict__ outp, int n) {
  int f = fa + fb;
  int idx = blockIdx.x * 256 + threadIdx.x;
  if (idx >= n * f) return;
  int node = idx / f, o = idx - node * f;
  outp[idx] = (o < fa) ? a[(size_t)node * fa + o] : b[(size_t)map[node] * fb + (o - fa)];
}

// ---------------- pad l2b / oW to JPAD with zeros
__global__ void k_padvec(const float* __restrict__ l2b, const float* __restrict__ oW,
                         float* __restrict__ l2bp, float* __restrict__ oWp) {
  int j = blockIdx.x * 256 + threadIdx.x;
  if (j >= JPAD) return;
  l2bp[j] = (j < JREAL) ? l2b[j] : 0.f;
  oWp[j]  = (j < JREAL) ? oW[j]  : 0.f;
}

// ---------------- pack l2W [256][6890] fp32 -> bf16 B-fragments
// layout: Bp[(t*8 + ks)*64 + lane][i] = l2W[ks*32 + (lane>>4)*8 + i][t*16 + (lane&15)]
__global__ void k_packB(const float* __restrict__ l2W, short8* __restrict__ Bp) {
  int idx = blockIdx.x * 256 + threadIdx.x;
  if (idx >= NTILE * 8 * 64) return;
  int l = idx & 63, ks = (idx >> 6) & 7, t = idx >> 9;
  int j = t * 16 + (l & 15);
  int kb = ks * 32 + ((l >> 4) << 3);
  short8 v;
#pragma unroll
  for (int i = 0; i < 8; ++i) {
    float f = (j < JREAL) ? l2W[(size_t)(kb + i) * JREAL + j] : 0.f;
    v[i] = (short)f2bf(f);
  }
  Bp[idx] = v;
}

// ---------------- fused MLP head with bf16 MFMA for the l2 GEMM
__global__ __launch_bounds__(256, 2) void k_final(
    const float* __restrict__ h, const float* __restrict__ l1W,
    const float* __restrict__ l1b, const short8* __restrict__ Bp,
    const float* __restrict__ l2bp, const float* __restrict__ oWp,
    const float* __restrict__ obp, float* __restrict__ out) {
  __shared__ float h1s[64][256];  // 64 KB
  const int tid = threadIdx.x;
  const int row0 = blockIdx.x * 64;

  // phase 1: h1[r][tid] = relu(h[r] . l1W[:,tid] + l1b[tid])  (fp32 VALU)
  {
    float wcol[32];
#pragma unroll
    for (int k = 0; k < 32; ++k) wcol[k] = l1W[k * 256 + tid];
    const float bt = l1b[tid];
    for (int r = 0; r < 64; ++r) {
      const float* hr = h + (size_t)(row0 + r) * 32;
      float s = bt;
#pragma unroll
      for (int k = 0; k < 32; ++k) s = fmaf(hr[k], wcol[k], s);
      h1s[r][tid] = fmaxf(s, 0.f);
    }
  }
  __syncthreads();

  const int w  = tid >> 6;      // wave id 0..3
  const int l  = tid & 63;      // lane
  const int lm = l & 15, lh = l >> 4;

  // A fragments: 64 rows x K=256 in registers (bf16), mapping mirrors k_packB
  short8 af[4][8];
#pragma unroll
  for (int rb = 0; rb < 4; ++rb)
#pragma unroll
    for (int ks = 0; ks < 8; ++ks) {
      const float* src = &h1s[rb * 16 + lm][ks * 32 + lh * 8];
      short8 a;
#pragma unroll
      for (int i = 0; i < 8; ++i) a[i] = (short)f2bf(src[i]);
      af[rb][ks] = a;
    }
  __syncthreads();  // h1s reads done; LDS reused as zred

  float zp[4][4];
#pragma unroll
  for (int rb = 0; rb < 4; ++rb)
#pragma unroll
    for (int r = 0; r < 4; ++r) zp[rb][r] = 0.f;

  const int t0 = w * (NTILE / 4);
  for (int tt = 0; tt < NTILE / 4; ++tt) {
    const int t = t0 + tt;
    const short8* bp = Bp + (size_t)t * 512 + l;
    short8 bfr[8];
#pragma unroll
    for (int ks = 0; ks < 8; ++ks) bfr[ks] = bp[ks * 64];

    f32x4 acc[4];
#pragma unroll
    for (int rb = 0; rb < 4; ++rb) acc[rb] = (f32x4){0.f, 0.f, 0.f, 0.f};

#pragma unroll
    for (int ks = 0; ks < 8; ++ks)
#pragma unroll
      for (int rb = 0; rb < 4; ++rb)
        acc[rb] = __builtin_amdgcn_mfma_f32_16x16x32_bf16(af[rb][ks], bfr[ks], acc[rb], 0, 0, 0);

    const int j = t * 16 + lm;
    const float lb = l2bp[j];
    const float ow = oWp[j];
#pragma unroll
    for (int rb = 0; rb < 4; ++rb)
#pragma unroll
      for (int r = 0; r < 4; ++r)
        zp[rb][r] += fmaxf(acc[rb][r] + lb, 0.f) * ow;
  }

#pragma unroll
  for (int m = 1; m < 16; m <<= 1)
#pragma unroll
    for (int rb = 0; rb < 4; ++rb)
#pragma unroll
      for (int r = 0; r < 4; ++r)
        zp[rb][r] += __shfl_xor(zp[rb][r], m);

  float* zred = &h1s[0][0];  // [4][64]
  if (lm == 0) {
#pragma unroll
    for (int rb = 0; rb < 4; ++rb)
#pragma unroll
      for (int r = 0; r < 4; ++r)
        zred[w * 64 + rb * 16 + lh * 4 + r] = zp[rb][r];
  }
  __syncthreads();
  if (tid < 64) {
    float z = zred[tid] + zred[64 + tid] + zred[128 + tid] + zred[192 + tid] + obp[0];
    out[row0 + tid] = 1.f / (1.f + expf(-z));
  }
}

// ================= host side =================
static void run_conv(const float* xin, const int* rp, const int* ss, int n, int fi, int fo,
                     const float* W, const float* U, const float* c, const float* b,
                     float* outp, float* xW, float* xU, hipStream_t stream) {
  int co = 4 * fo;
  k_matmul<<<(n * co + 255) / 256, 256, 0, stream>>>(xin, W, xW, n, fi, co);
  k_matmul<<<(n * 4 + 255) / 256, 256, 0, stream>>>(xin, U, xU, n, fi, 4);
  k_attagg<<<(n * fo + 255) / 256, 256, 0, stream>>>(rp, ss, xW, xU, c, b, outp, n, fo);
}

static void build_csr(const int* ei, int E, int n, int* deg, int* cur, int* rp, int* ss,
                      hipStream_t stream) {
  const int* src = ei;
  const int* dst = ei + E;
  k_hist<<<(E + 255) / 256, 256, 0, stream>>>(dst, deg, E);
  k_scan<<<1, 1024, 0, stream>>>(deg, rp, n);
  k_scatter<<<(E + 255) / 256, 256, 0, stream>>>(src, dst, rp, cur, ss, E);
}

extern "C" void kernel_launch(void* const* d_in, const int* in_sizes, int n_in,
                              void* d_out, int out_size, void* d_ws, size_t ws_size,
                              hipStream_t stream) {
  const float* x   = (const float*)d_in[0];
  const int* ei1   = (const int*)d_in[1];
  const int* ei2   = (const int*)d_in[2];
  const int* ei3   = (const int*)d_in[3];
  const int* cl1   = (const int*)d_in[4];
  const int* cl2   = (const int*)d_in[5];
  const float* cW1 = (const float*)d_in[6],  *cU1 = (const float*)d_in[7],
             * cc1 = (const float*)d_in[8],  *cb1 = (const float*)d_in[9];
  const float* cW2 = (const float*)d_in[10], *cU2 = (const float*)d_in[11],
             * cc2 = (const float*)d_in[12], *cb2 = (const float*)d_in[13];
  const float* cW3 = (const float*)d_in[14], *cU3 = (const float*)d_in[15],
             * cc3 = (const float*)d_in[16], *cb3 = (const float*)d_in[17];
  const float* cW4 = (const float*)d_in[18], *cU4 = (const float*)d_in[19],
             * cc4 = (const float*)d_in[20], *cb4 = (const float*)d_in[21];
  const float* cW5 = (const float*)d_in[22], *cU5 = (const float*)d_in[23],
             * cc5 = (const float*)d_in[24], *cb5 = (const float*)d_in[25];
  const float* l1W = (const float*)d_in[26], *l1b = (const float*)d_in[27];
  const float* l2W = (const float*)d_in[28], *l2b = (const float*)d_in[29];
  const float* oW  = (const float*)d_in[30], *ob  = (const float*)d_in[31];

  float* ws = (float*)d_ws;
  // ---- zeroed region: [0, 780000) floats ----
  float* x2p  = ws + 0;        // NN2*16 = 320000 (segmax out, needs zeros)
  float* x3p  = ws + 320000;   // NN3*32 = 320000 (segmax out, needs zeros)
  int*  deg1  = (int*)(ws + 640000);  // N1
  int*  cur1  = (int*)(ws + 680000);  // N1
  int*  deg2  = (int*)(ws + 720000);  // NN2
  int*  cur2  = (int*)(ws + 740000);  // NN2
  int*  deg3  = (int*)(ws + 760000);  // NN3
  int*  cur3  = (int*)(ws + 770000);  // NN3
  // ---- end zeroed region ----
  int*  rp1   = (int*)(ws + 780000);  // N1+1
  int*  rp2   = (int*)(ws + 820064);  // NN2+1
  int*  rp3   = (int*)(ws + 840128);  // NN3+1
  int*  ss1   = (int*)(ws + 850144);  // EE1
  int*  ss2   = (int*)(ws + 1490144); // EE2
  int*  ss3   = (int*)(ws + 1810144); // EE3
  float* x1   = ws + 1970144;  // N1*16
  float* x2   = ws + 2610144;  // NN2*32
  float* x5   = ws + 3250144;  // NN2*16
  float* x3a  = ws + 3570144;  // NN3*64
  float* x3b  = ws + 4210144;  // NN3*32
  float* xcat = ws + 4530144;  // NN2*64 ; ALIASED: reused as h [N1*32] after conv5
  float* h    = xcat;          // same 1,280,000-float region (safe: xcat dead by then)
  short8* Bp  = (short8*)(ws + 5810144);  // 432*8*64 frags = 884,736 f32 slots
  float* l2bp = ws + 6694880;  // JPAD
  float* oWp  = ws + 6701792;  // JPAD
  float* xW   = ws + 6708704;  // up to 2,560,000 (overwritten per conv)
  float* xU   = ws + 9268704;  // up to 160,000
  // total = 9,428,704 floats = 37.7 MB

  hipMemsetAsync(ws, 0, 780000 * sizeof(float), stream);
  k_padvec<<<(JPAD + 255) / 256, 256, 0, stream>>>(l2b, oW, l2bp, oWp);
  k_packB<<<(NTILE * 8 * 64 + 255) / 256, 256, 0, stream>>>(l2W, Bp);

  // CSR for the three edge sets
  build_csr(ei1, EE1, N1,  deg1, cur1, rp1, ss1, stream);
  build_csr(ei2, EE2, NN2, deg2, cur2, rp2, ss2, stream);
  build_csr(ei3, EE3, NN3, deg3, cur3, rp3, ss3, stream);

  // conv1: x [N1,5] -> x1 [N1,16]
  run_conv(x, rp1, ss1, N1, 5, 16, cW1, cU1, cc1, cb1, x1, xW, xU, stream);
  // pool1
  k_segmax<<<(N1 * 16 + 255) / 256, 256, 0, stream>>>(x1, cl1, x2p, N1, 16);
  // conv2: x2p [NN2,16] -> x2 [NN2,32]
  run_conv(x2p, rp2, ss2, NN2, 16, 32, cW2, cU2, cc2, cb2, x2, xW, xU, stream);
  // pool2
  k_segmax<<<(NN2 * 32 + 255) / 256, 256, 0, stream>>>(x2, cl2, x3p, NN2, 32);
  // conv3: x3p [NN3,32] -> x3a [NN3,64]
  run_conv(x3p, rp3, ss3, NN3, 32, 64, cW3, cU3, cc3, cb3, x3a, xW, xU, stream);
  // conv4: x3a [NN3,64] -> x3b [NN3,32]
  run_conv(x3a, rp3, ss3, NN3, 64, 32, cW4, cU4, cc4, cb4, x3b, xW, xU, stream);
  // unpool + skip: xcat [NN2,64]
  k_cat<<<(NN2 * 64 + 255) / 256, 256, 0, stream>>>(x2, 32, x3b, 32, cl2, xcat, NN2);
  // conv5: xcat [NN2,64] -> x5 [NN2,16]
  run_conv(xcat, rp2, ss2, NN2, 64, 16, cW5, cU5, cc5, cb5, x5, xW, xU, stream);
  // h = concat(x1, x5[cluster1]) [N1,32]  (overwrites xcat region — xcat is dead)
  k_cat<<<(N1 * 32 + 255) / 256, 256, 0, stream>>>(x1, 16, x5, 16, cl1, h, N1);
  // fused MLP head -> out
  k_final<<<N1 / 64, 256, 0, stream>>>(h, l1W, l1b, Bp, l2bp, oWp, ob, (float*)d_out);
}

// Round 4
// 743.550 us; speedup vs baseline: 6.4727x; 1.1136x over previous
//
#include <hip/hip_runtime.h>
#include <math.h>

#define N1  40000
#define NN2 20000
#define NN3 10000
#define EE1 640000
#define EE2 320000
#define EE3 160000
#define JPAD 6912   // 6890 padded to 432 tiles of 16
#define JREAL 6890
#define NTILE 432   // JPAD/16
#define CSPLIT 4
#define TPB (NTILE/CSPLIT)   // 108 tiles per col-group
#define NROWP 40192          // 157*256 row pad
#define NGRP 628             // NROWP/64

typedef __attribute__((ext_vector_type(8))) short short8;
typedef __attribute__((ext_vector_type(4))) float f32x4;

__device__ inline unsigned short f2bf(float f) {
  unsigned u = __float_as_uint(f);
  u += 0x7FFF + ((u >> 16) & 1);   // round-to-nearest-even
  return (unsigned short)(u >> 16);
}

// ---------------- fused node-transform GEMMs: xW = X@W [n,co], xU = X@U [n,4]
__global__ void k_matmulWU(const float* __restrict__ X, const float* __restrict__ W,
                           const float* __restrict__ U, float* __restrict__ xW,
                           float* __restrict__ xU, int n, int ci, int co) {
  int ct = co + 4;
  int idx = blockIdx.x * 256 + threadIdx.x;
  if (idx >= n * ct) return;
  int row = idx / ct, col = idx - row * ct;
  const float* xr = X + (size_t)row * ci;
  const float* M;
  int stride;
  if (col < co) { M = W + col; stride = co; }
  else          { M = U + (col - co); stride = 4; }
  float s = 0.f;
  for (int k = 0; k < ci; ++k) s = fmaf(xr[k], M[(size_t)k * stride], s);
  if (col < co) xW[(size_t)row * co + col] = s;
  else          xU[(size_t)row * 4 + (col - co)] = s;
}

// ---------------- CSR build (all 3 edge sets in one kernel): histogram
__global__ void k_hist3(const int* __restrict__ d1, const int* __restrict__ d2,
                        const int* __restrict__ d3, int* __restrict__ g1,
                        int* __restrict__ g2, int* __restrict__ g3) {
  int e = blockIdx.x * 256 + threadIdx.x;
  if (e < EE1) { atomicAdd(&g1[d1[e]], 1); return; }
  e -= EE1;
  if (e < EE2) { atomicAdd(&g2[d2[e]], 1); return; }
  e -= EE2;
  if (e < EE3) atomicAdd(&g3[d3[e]], 1);
}

// ---------------- CSR build: 3 concurrent single-block scans
__global__ __launch_bounds__(1024) void k_scan3(
    const int* __restrict__ g1, const int* __restrict__ g2, const int* __restrict__ g3,
    int* __restrict__ r1, int* __restrict__ r2, int* __restrict__ r3) {
  const int* deg; int* rp; int n;
  if (blockIdx.x == 0)      { deg = g1; rp = r1; n = N1; }
  else if (blockIdx.x == 1) { deg = g2; rp = r2; n = NN2; }
  else                      { deg = g3; rp = r3; n = NN3; }
  __shared__ int ssum[1024];
  const int tid = threadIdx.x;
  const int per = (n + 1023) >> 10;
  const int lo = tid * per, hi = min(lo + per, n);
  int s = 0;
  for (int i = lo; i < hi; ++i) s += deg[i];
  ssum[tid] = s;
  __syncthreads();
  for (int off = 1; off < 1024; off <<= 1) {
    int v = (tid >= off) ? ssum[tid - off] : 0;
    __syncthreads();
    ssum[tid] += v;
    __syncthreads();
  }
  int carry = (tid == 0) ? 0 : ssum[tid - 1];
  for (int i = lo; i < hi; ++i) { rp[i] = carry; carry += deg[i]; }
  if (tid == 1023) rp[n] = carry;
}

// ---------------- CSR build: scatter src ids + record each edge's CSR slot
__global__ void k_scatter3(const int* __restrict__ ei1, const int* __restrict__ ei2,
                           const int* __restrict__ ei3, const int* __restrict__ r1,
                           const int* __restrict__ r2, const int* __restrict__ r3,
                           int* __restrict__ c1, int* __restrict__ c2, int* __restrict__ c3,
                           int* __restrict__ s1, int* __restrict__ s2, int* __restrict__ s3,
                           int* __restrict__ p1, int* __restrict__ p2, int* __restrict__ p3) {
  int e = blockIdx.x * 256 + threadIdx.x;
  const int* ei; const int* rp; int* cur; int* ss; int* ep; int E;
  if (e < EE1) { ei = ei1; rp = r1; cur = c1; ss = s1; ep = p1; E = EE1; }
  else {
    e -= EE1;
    if (e < EE2) { ei = ei2; rp = r2; cur = c2; ss = s2; ep = p2; E = EE2; }
    else {
      e -= EE2;
      if (e >= EE3) return;
      ei = ei3; rp = r3; cur = c3; ss = s3; ep = p3; E = EE3;
    }
  }
  int d = ei[E + e];
  int pos = rp[d] + atomicAdd(&cur[d], 1);
  ss[pos] = ei[e];
  ep[e] = pos;
}

// ---------------- per-edge attention weights, written in CSR order
__global__ void k_edgeq(const int* __restrict__ ei, const int* __restrict__ ep,
                        const float* __restrict__ xU, const float* __restrict__ c,
                        float4* __restrict__ qcsr, int E) {
  int e = blockIdx.x * 256 + threadIdx.x;
  if (e >= E) return;
  int s = ei[e], d = ei[E + e];
  float4 a = *(const float4*)&xU[(size_t)s * 4];
  float4 b = *(const float4*)&xU[(size_t)d * 4];
  float l0 = a.x - b.x + c[0], l1 = a.y - b.y + c[1];
  float l2 = a.z - b.z + c[2], l3 = a.w - b.w + c[3];
  float mx = fmaxf(fmaxf(l0, l1), fmaxf(l2, l3));
  float q0 = __expf(l0 - mx), q1 = __expf(l1 - mx);
  float q2 = __expf(l2 - mx), q3 = __expf(l3 - mx);
  float inv = 1.f / (q0 + q1 + q2 + q3);
  qcsr[ep[e]] = make_float4(q0 * inv, q1 * inv, q2 * inv, q3 * inv);
}

// ---------------- fused FeaSt aggregation (q precomputed)
__global__ void k_attagg2(const int* __restrict__ rp, const int* __restrict__ ss,
                          const float4* __restrict__ qcsr, const float* __restrict__ xW,
                          const float* __restrict__ c, const float* __restrict__ b,
                          float* __restrict__ outp, int n, int fo) {
  int idx = blockIdx.x * 256 + threadIdx.x;
  if (idx >= n * fo) return;
  int d = idx / fo, o = idx - d * fo;
  const int e0 = rp[d], e1 = rp[d + 1];
  float acc = 0.f;
  for (int e = e0; e < e1; ++e) {
    int s = ss[e];
    float4 q = qcsr[e];
    const float* m = xW + (size_t)s * 4 * fo + o;
    acc += q.x * m[0] + q.y * m[fo] + q.z * m[2 * fo] + q.w * m[3 * fo];
  }
  // self-loop: q = softmax(c)
  {
    float c0 = c[0], c1 = c[1], c2 = c[2], c3 = c[3];
    float mx = fmaxf(fmaxf(c0, c1), fmaxf(c2, c3));
    float q0 = __expf(c0 - mx), q1 = __expf(c1 - mx);
    float q2 = __expf(c2 - mx), q3 = __expf(c3 - mx);
    float inv = 1.f / (q0 + q1 + q2 + q3);
    const float* m = xW + (size_t)d * 4 * fo + o;
    acc += (q0 * m[0] + q1 * m[fo] + q2 * m[2 * fo] + q3 * m[3 * fo]) * inv;
  }
  outp[idx] = fmaxf(acc / (float)(e1 - e0 + 1) + b[o], 0.f);
}

// ---------------- graclus-style segment max (values >= 0, out pre-zeroed)
__global__ void k_segmax(const float* __restrict__ xin, const int* __restrict__ cl,
                         float* __restrict__ outp, int n, int f) {
  int idx = blockIdx.x * 256 + threadIdx.x;
  if (idx >= n * f) return;
  int node = idx / f, o = idx - node * f;
  atomicMax((int*)&outp[(size_t)cl[node] * f + o], __float_as_int(xin[idx]));
}

// ---------------- concat: out[n, 0:fa] = a[n], out[n, fa:fa+fb] = b[map[n]]
__global__ void k_cat(const float* __restrict__ a, int fa, const float* __restrict__ b, int fb,
                      const int* __restrict__ map, float* __restrict__ outp, int n) {
  int f = fa + fb;
  int idx = blockIdx.x * 256 + threadIdx.x;
  if (idx >= n * f) return;
  int node = idx / f, o = idx - node * f;
  outp[idx] = (o < fa) ? a[(size_t)node * fa + o] : b[(size_t)map[node] * fb + (o - fa)];
}

// ---------------- pad l2b / oW to JPAD with zeros
__global__ void k_padvec(const float* __restrict__ l2b, const float* __restrict__ oW,
                         float* __restrict__ l2bp, float* __restrict__ oWp) {
  int j = blockIdx.x * 256 + threadIdx.x;
  if (j >= JPAD) return;
  l2bp[j] = (j < JREAL) ? l2b[j] : 0.f;
  oWp[j]  = (j < JREAL) ? oW[j]  : 0.f;
}

// ---------------- pack l2W [256][6890] fp32 -> bf16 B-fragments
// Bp[(t*8 + ks)*64 + lane][i] = l2W[ks*32 + (lane>>4)*8 + i][t*16 + (lane&15)]
__global__ void k_packB(const float* __restrict__ l2W, short8* __restrict__ Bp) {
  int idx = blockIdx.x * 256 + threadIdx.x;
  if (idx >= NTILE * 8 * 64) return;
  int l = idx & 63, ks = (idx >> 6) & 7, t = idx >> 9;
  int j = t * 16 + (l & 15);
  int kb = ks * 32 + ((l >> 4) << 3);
  short8 v;
#pragma unroll
  for (int i = 0; i < 8; ++i) {
    float f = (j < JREAL) ? l2W[(size_t)(kb + i) * JREAL + j] : 0.f;
    v[i] = (short)f2bf(f);
  }
  Bp[idx] = v;
}

// ---------------- h-build + l1 GEMM + relu + bf16 A-fragment pack
// one block per 64-row group; h[row] = concat(x1[row], x5[cl1[row]])
__global__ __launch_bounds__(256) void k_packh(
    const float* __restrict__ x1, const float* __restrict__ x5,
    const int* __restrict__ cl1, const float* __restrict__ l1W,
    const float* __restrict__ l1b, short8* __restrict__ Apack) {
  __shared__ float h1s[64][256];  // XOR-swizzled columns, 64 KB
  const int tid = threadIdx.x;
  const int row0 = blockIdx.x * 64;

  float wcol[32];
#pragma unroll
  for (int k = 0; k < 32; ++k) wcol[k] = l1W[k * 256 + tid];
  const float bt = l1b[tid];

  for (int r = 0; r < 64; ++r) {
    const int row = row0 + r;
    float s = bt;
    if (row < N1) {
      const float* a = x1 + (size_t)row * 16;
      const float* b = x5 + (size_t)cl1[row] * 16;
#pragma unroll
      for (int k = 0; k < 16; ++k) s = fmaf(a[k], wcol[k], s);
#pragma unroll
      for (int k = 0; k < 16; ++k) s = fmaf(b[k], wcol[16 + k], s);
    }
    h1s[r][tid ^ ((r & 7) << 3)] = fmaxf(s, 0.f);
  }
  __syncthreads();

  // pack: slot s = rb*512 + ks*64 + l -> Apack[g*2048 + s]
#pragma unroll
  for (int j = 0; j < 8; ++j) {
    int s = j * 256 + tid;
    int l = s & 63, ks = (s >> 6) & 7, rb = s >> 9;
    int row = rb * 16 + (l & 15);
    int col0 = (ks * 32 + ((l >> 4) << 3)) ^ ((row & 7) << 3);
    const float* sp = &h1s[row][col0];
    short8 v;
#pragma unroll
    for (int i = 0; i < 8; ++i) v[i] = (short)f2bf(sp[i]);
    Apack[(size_t)blockIdx.x * 2048 + s] = v;
  }
}

// ---------------- l2 GEMM + relu + .oW epilogue (bf16 MFMA, LDS-staged B)
// grid = 157 row-groups x 4 col-groups; block = 4 waves x 64 rows; partial z -> atomicAdd
__global__ __launch_bounds__(256, 2) void k_final2(
    const short8* __restrict__ Apack, const short8* __restrict__ Bp,
    const float* __restrict__ l2bp, const float* __restrict__ oWp,
    float* __restrict__ zbuf) {
  __shared__ short8 bufs[2][512];   // 16 KB double buffer
  const int tid = threadIdx.x, wid = tid >> 6, l = tid & 63;
  const int rg = blockIdx.x >> 2, cg = blockIdx.x & 3;
  const int lm = l & 15, lh = l >> 4;

  // A fragments for this wave's 64 rows (coalesced global reads)
  short8 af[4][8];
  {
    const short8* ap = Apack + (size_t)(rg * 4 + wid) * 2048 + l;
#pragma unroll
    for (int rb = 0; rb < 4; ++rb)
#pragma unroll
      for (int ks = 0; ks < 8; ++ks) af[rb][ks] = ap[rb * 512 + ks * 64];
  }

  const short8* bsrc = Bp + (size_t)cg * TPB * 512;
  // prolog: tile 0 -> buf0; tile 1 -> regs
  short8 n0 = bsrc[tid], n1 = bsrc[256 + tid];
  bufs[0][tid] = n0; bufs[0][256 + tid] = n1;
  n0 = bsrc[512 + tid]; n1 = bsrc[768 + tid];
  __syncthreads();

  float zp[4][4];
#pragma unroll
  for (int rb = 0; rb < 4; ++rb)
#pragma unroll
    for (int r = 0; r < 4; ++r) zp[rb][r] = 0.f;

  for (int tt = 0; tt < TPB; ++tt) {
    const int cur = tt & 1;
    if (tt + 1 < TPB) {           // write-late: tile tt+1 into the other buffer
      bufs[cur ^ 1][tid] = n0;
      bufs[cur ^ 1][256 + tid] = n1;
    }
    if (tt + 2 < TPB) {           // issue-early: tile tt+2 into regs
      n0 = bsrc[(tt + 2) * 512 + tid];
      n1 = bsrc[(tt + 2) * 512 + 256 + tid];
    }
    short8 bfr[8];
#pragma unroll
    for (int ks = 0; ks < 8; ++ks) bfr[ks] = bufs[cur][ks * 64 + l];

    f32x4 acc[4];
#pragma unroll
    for (int rb = 0; rb < 4; ++rb) acc[rb] = (f32x4){0.f, 0.f, 0.f, 0.f};
#pragma unroll
    for (int ks = 0; ks < 8; ++ks)
#pragma unroll
      for (int rb = 0; rb < 4; ++rb)
        acc[rb] = __builtin_amdgcn_mfma_f32_16x16x32_bf16(af[rb][ks], bfr[ks], acc[rb], 0, 0, 0);

    const int j = (cg * TPB + tt) * 16 + lm;
    const float lb = l2bp[j];
    const float ow = oWp[j];
#pragma unroll
    for (int rb = 0; rb < 4; ++rb)
#pragma unroll
      for (int r = 0; r < 4; ++r)
        zp[rb][r] += fmaxf(acc[rb][r] + lb, 0.f) * ow;
    __syncthreads();
  }

  // reduce over the 16 column-lanes
#pragma unroll
  for (int m = 1; m < 16; m <<= 1)
#pragma unroll
    for (int rb = 0; rb < 4; ++rb)
#pragma unroll
      for (int r = 0; r < 4; ++r)
        zp[rb][r] += __shfl_xor(zp[rb][r], m);

  if (lm == 0) {
    const int rbase = rg * 256 + wid * 64 + lh * 4;
#pragma unroll
    for (int rb = 0; rb < 4; ++rb)
#pragma unroll
      for (int r = 0; r < 4; ++r)
        atomicAdd(&zbuf[rbase + rb * 16 + r], zp[rb][r]);
  }
}

// ---------------- final sigmoid
__global__ void k_sigm(const float* __restrict__ zbuf, const float* __restrict__ ob,
                       float* __restrict__ out) {
  int i = blockIdx.x * 256 + threadIdx.x;
  if (i >= N1) return;
  out[i] = 1.f / (1.f + expf(-(zbuf[i] + ob[0])));
}

// ================= host side =================
static void run_conv(const float* xin, const int* ei, const int* ep, int E,
                     const int* rp, const int* ss, int n, int ci, int fo,
                     const float* W, const float* U, const float* c, const float* b,
                     float* outp, float* xW, float* xU, float4* qcsr, hipStream_t stream) {
  int co = 4 * fo;
  k_matmulWU<<<(n * (co + 4) + 255) / 256, 256, 0, stream>>>(xin, W, U, xW, xU, n, ci, co);
  k_edgeq<<<(E + 255) / 256, 256, 0, stream>>>(ei, ep, xU, c, qcsr, E);
  k_attagg2<<<(n * fo + 255) / 256, 256, 0, stream>>>(rp, ss, qcsr, xW, c, b, outp, n, fo);
}

extern "C" void kernel_launch(void* const* d_in, const int* in_sizes, int n_in,
                              void* d_out, int out_size, void* d_ws, size_t ws_size,
                              hipStream_t stream) {
  const float* x   = (const float*)d_in[0];
  const int* ei1   = (const int*)d_in[1];
  const int* ei2   = (const int*)d_in[2];
  const int* ei3   = (const int*)d_in[3];
  const int* cl1   = (const int*)d_in[4];
  const int* cl2   = (const int*)d_in[5];
  const float* cW1 = (const float*)d_in[6],  *cU1 = (const float*)d_in[7],
             * cc1 = (const float*)d_in[8],  *cb1 = (const float*)d_in[9];
  const float* cW2 = (const float*)d_in[10], *cU2 = (const float*)d_in[11],
             * cc2 = (const float*)d_in[12], *cb2 = (const float*)d_in[13];
  const float* cW3 = (const float*)d_in[14], *cU3 = (const float*)d_in[15],
             * cc3 = (const float*)d_in[16], *cb3 = (const float*)d_in[17];
  const float* cW4 = (const float*)d_in[18], *cU4 = (const float*)d_in[19],
             * cc4 = (const float*)d_in[20], *cb4 = (const float*)d_in[21];
  const float* cW5 = (const float*)d_in[22], *cU5 = (const float*)d_in[23],
             * cc5 = (const float*)d_in[24], *cb5 = (const float*)d_in[25];
  const float* l1W = (const float*)d_in[26], *l1b = (const float*)d_in[27];
  const float* l2W = (const float*)d_in[28], *l2b = (const float*)d_in[29];
  const float* oW  = (const float*)d_in[30], *ob  = (const float*)d_in[31];

  float* ws = (float*)d_ws;
  // ---- zeroed region: [0, 820192) floats ----
  float* x2p  = ws + 0;        // NN2*16
  float* x3p  = ws + 320000;   // NN3*32
  float* zbuf = ws + 640000;   // NROWP
  int*  deg1  = (int*)(ws + 680192);  // N1
  int*  cur1  = (int*)(ws + 720192);  // N1
  int*  deg2  = (int*)(ws + 760192);  // NN2
  int*  cur2  = (int*)(ws + 780192);  // NN2
  int*  deg3  = (int*)(ws + 800192);  // NN3
  int*  cur3  = (int*)(ws + 810192);  // NN3
  // ---- end zeroed region ----
  int*  rp1   = (int*)(ws + 820192);  // N1+1
  int*  rp2   = (int*)(ws + 860256);  // NN2+1
  int*  rp3   = (int*)(ws + 880320);  // NN3+1
  int*  ss1   = (int*)(ws + 890368);  // EE1
  int*  ss2   = (int*)(ws + 1530368); // EE2
  int*  ss3   = (int*)(ws + 1850368); // EE3
  int*  ep1   = (int*)(ws + 2010368); // EE1
  int*  ep2   = (int*)(ws + 2650368); // EE2
  int*  ep3   = (int*)(ws + 2970368); // EE3
  float* x1   = ws + 3130368;  // N1*16
  float* x2   = ws + 3770368;  // NN2*32
  float* x5   = ws + 4410368;  // NN2*16
  float* x3a  = ws + 4730368;  // NN3*64
  float* x3b  = ws + 5370368;  // NN3*32
  float* xcat = ws + 5690368;  // NN2*64
  short8* Bp  = (short8*)(ws + 6970368);  // 432*8*64 frags = 884,736 f32 slots
  float* l2bp = ws + 7855104;  // JPAD
  float* oWp  = ws + 7862016;  // JPAD
  float4* qcsr= (float4*)(ws + 7868928);  // EE1*4 = 2,560,000
  float* xW   = ws + 10428928; // up to 2,560,000 (per conv)
  float* xU   = ws + 12988928; // up to 160,000
  // Apack aliases [qcsr .. end): needs 5,144,576 <= 5,280,000 floats (qcsr+xW+xU);
  // qcsr/xW/xU are dead once conv5 finishes, k_packh runs after.
  short8* Apack = (short8*)(ws + 7868928);
  // total = 13,148,928 floats = 52.6 MB

  hipMemsetAsync(ws, 0, 820192 * sizeof(float), stream);
  k_padvec<<<(JPAD + 255) / 256, 256, 0, stream>>>(l2b, oW, l2bp, oWp);
  k_packB<<<(NTILE * 8 * 64 + 255) / 256, 256, 0, stream>>>(l2W, Bp);

  // CSR for the three edge sets (fused kernels)
  const int ET = EE1 + EE2 + EE3;
  k_hist3<<<(ET + 255) / 256, 256, 0, stream>>>(ei1 + EE1, ei2 + EE2, ei3 + EE3,
                                                deg1, deg2, deg3);
  k_scan3<<<3, 1024, 0, stream>>>(deg1, deg2, deg3, rp1, rp2, rp3);
  k_scatter3<<<(ET + 255) / 256, 256, 0, stream>>>(ei1, ei2, ei3, rp1, rp2, rp3,
                                                   cur1, cur2, cur3, ss1, ss2, ss3,
                                                   ep1, ep2, ep3);

  // conv1: x [N1,5] -> x1 [N1,16]
  run_conv(x, ei1, ep1, EE1, rp1, ss1, N1, 5, 16, cW1, cU1, cc1, cb1, x1, xW, xU, qcsr, stream);
  k_segmax<<<(N1 * 16 + 255) / 256, 256, 0, stream>>>(x1, cl1, x2p, N1, 16);
  // conv2: x2p [NN2,16] -> x2 [NN2,32]
  run_conv(x2p, ei2, ep2, EE2, rp2, ss2, NN2, 16, 32, cW2, cU2, cc2, cb2, x2, xW, xU, qcsr, stream);
  k_segmax<<<(NN2 * 32 + 255) / 256, 256, 0, stream>>>(x2, cl2, x3p, NN2, 32);
  // conv3: x3p [NN3,32] -> x3a [NN3,64]
  run_conv(x3p, ei3, ep3, EE3, rp3, ss3, NN3, 32, 64, cW3, cU3, cc3, cb3, x3a, xW, xU, qcsr, stream);
  // conv4: x3a [NN3,64] -> x3b [NN3,32]
  run_conv(x3a, ei3, ep3, EE3, rp3, ss3, NN3, 64, 32, cW4, cU4, cc4, cb4, x3b, xW, xU, qcsr, stream);
  // unpool + skip: xcat [NN2,64]
  k_cat<<<(NN2 * 64 + 255) / 256, 256, 0, stream>>>(x2, 32, x3b, 32, cl2, xcat, NN2);
  // conv5: xcat [NN2,64] -> x5 [NN2,16]
  run_conv(xcat, ei2, ep2, EE2, rp2, ss2, NN2, 64, 16, cW5, cU5, cc5, cb5, x5, xW, xU, qcsr, stream);

  // MLP head: pack h1 A-frags, MFMA GEMM with fused relu.oW, sigmoid
  k_packh<<<NGRP, 256, 0, stream>>>(x1, x5, cl1, l1W, l1b, Apack);
  k_final2<<<(NROWP / 256) * CSPLIT, 256, 0, stream>>>(Apack, Bp, l2bp, oWp, zbuf);
  k_sigm<<<(N1 + 255) / 256, 256, 0, stream>>>(zbuf, ob, (float*)d_out);
}

// Round 5
// 716.078 us; speedup vs baseline: 6.7211x; 1.0384x over previous
//
#include <hip/hip_runtime.h>
#include <math.h>

#define N1  40000
#define NN2 20000
#define NN3 10000
#define EE1 640000
#define EE2 320000
#define EE3 160000
#define JPAD 6912   // 6890 padded to 432 tiles of 16
#define JREAL 6890
#define NTILE 432   // JPAD/16
#define CSPLIT 4
#define TPB (NTILE/CSPLIT)   // 108 tiles per col-group
#define NSTG (TPB/2)         // 54 two-tile stages
#define NROWP 40192          // 157*256 row pad
#define NGRP 628             // NROWP/64

typedef __attribute__((ext_vector_type(8))) short short8;
typedef __attribute__((ext_vector_type(4))) float f32x4;

__device__ inline unsigned short f2bf(float f) {
  unsigned u = __float_as_uint(f);
  u += 0x7FFF + ((u >> 16) & 1);   // round-to-nearest-even
  return (unsigned short)(u >> 16);
}

// ---------------- node-transform GEMMs with optional concat-gather input:
// row features = [Xa[row][0:fa] | Xb[map[row]][0:fb]]; xW = X@W [n,co], xU = X@U [n,4]
__global__ void k_matmulWU(const float* __restrict__ Xa, int fa,
                           const float* __restrict__ Xb, int fb,
                           const int* __restrict__ map,
                           const float* __restrict__ W, const float* __restrict__ U,
                           float* __restrict__ xW, float* __restrict__ xU,
                           int n, int co) {
  int ct = co + 4;
  int idx = blockIdx.x * 256 + threadIdx.x;
  if (idx >= n * ct) return;
  int row = idx / ct, col = idx - row * ct;
  const float* M;
  int stride;
  if (col < co) { M = W + col; stride = co; }
  else          { M = U + (col - co); stride = 4; }
  float s = 0.f;
  const float* ar = Xa + (size_t)row * fa;
  for (int k = 0; k < fa; ++k) s = fmaf(ar[k], M[(size_t)k * stride], s);
  if (Xb) {
    const float* br = Xb + (size_t)map[row] * fb;
    for (int k = 0; k < fb; ++k) s = fmaf(br[k], M[(size_t)(fa + k) * stride], s);
  }
  if (col < co) xW[(size_t)row * co + col] = s;
  else          xU[(size_t)row * 4 + (col - co)] = s;
}

// ---------------- CSR build (all 3 edge sets in one kernel): histogram
__global__ void k_hist3(const int* __restrict__ d1, const int* __restrict__ d2,
                        const int* __restrict__ d3, int* __restrict__ g1,
                        int* __restrict__ g2, int* __restrict__ g3) {
  int e = blockIdx.x * 256 + threadIdx.x;
  if (e < EE1) { atomicAdd(&g1[d1[e]], 1); return; }
  e -= EE1;
  if (e < EE2) { atomicAdd(&g2[d2[e]], 1); return; }
  e -= EE2;
  if (e < EE3) atomicAdd(&g3[d3[e]], 1);
}

// ---------------- CSR build: 3 concurrent single-block scans
__global__ __launch_bounds__(1024) void k_scan3(
    const int* __restrict__ g1, const int* __restrict__ g2, const int* __restrict__ g3,
    int* __restrict__ r1, int* __restrict__ r2, int* __restrict__ r3) {
  const int* deg; int* rp; int n;
  if (blockIdx.x == 0)      { deg = g1; rp = r1; n = N1; }
  else if (blockIdx.x == 1) { deg = g2; rp = r2; n = NN2; }
  else                      { deg = g3; rp = r3; n = NN3; }
  __shared__ int ssum[1024];
  const int tid = threadIdx.x;
  const int per = (n + 1023) >> 10;
  const int lo = tid * per, hi = min(lo + per, n);
  int s = 0;
  for (int i = lo; i < hi; ++i) s += deg[i];
  ssum[tid] = s;
  __syncthreads();
  for (int off = 1; off < 1024; off <<= 1) {
    int v = (tid >= off) ? ssum[tid - off] : 0;
    __syncthreads();
    ssum[tid] += v;
    __syncthreads();
  }
  int carry = (tid == 0) ? 0 : ssum[tid - 1];
  for (int i = lo; i < hi; ++i) { rp[i] = carry; carry += deg[i]; }
  if (tid == 1023) rp[n] = carry;
}

// ---------------- CSR build: scatter src ids + record each edge's CSR slot
__global__ void k_scatter3(const int* __restrict__ ei1, const int* __restrict__ ei2,
                           const int* __restrict__ ei3, const int* __restrict__ r1,
                           const int* __restrict__ r2, const int* __restrict__ r3,
                           int* __restrict__ c1, int* __restrict__ c2, int* __restrict__ c3,
                           int* __restrict__ s1, int* __restrict__ s2, int* __restrict__ s3,
                           int* __restrict__ p1, int* __restrict__ p2, int* __restrict__ p3) {
  int e = blockIdx.x * 256 + threadIdx.x;
  const int* ei; const int* rp; int* cur; int* ss; int* ep; int E;
  if (e < EE1) { ei = ei1; rp = r1; cur = c1; ss = s1; ep = p1; E = EE1; }
  else {
    e -= EE1;
    if (e < EE2) { ei = ei2; rp = r2; cur = c2; ss = s2; ep = p2; E = EE2; }
    else {
      e -= EE2;
      if (e >= EE3) return;
      ei = ei3; rp = r3; cur = c3; ss = s3; ep = p3; E = EE3;
    }
  }
  int d = ei[E + e];
  int pos = rp[d] + atomicAdd(&cur[d], 1);
  ss[pos] = ei[e];
  ep[e] = pos;
}

// ---------------- per-edge attention weights, written in CSR order
__global__ void k_edgeq(const int* __restrict__ ei, const int* __restrict__ ep,
                        const float* __restrict__ xU, const float* __restrict__ c,
                        float4* __restrict__ qcsr, int E) {
  int e = blockIdx.x * 256 + threadIdx.x;
  if (e >= E) return;
  int s = ei[e], d = ei[E + e];
  float4 a = *(const float4*)&xU[(size_t)s * 4];
  float4 b = *(const float4*)&xU[(size_t)d * 4];
  float l0 = a.x - b.x + c[0], l1 = a.y - b.y + c[1];
  float l2 = a.z - b.z + c[2], l3 = a.w - b.w + c[3];
  float mx = fmaxf(fmaxf(l0, l1), fmaxf(l2, l3));
  float q0 = __expf(l0 - mx), q1 = __expf(l1 - mx);
  float q2 = __expf(l2 - mx), q3 = __expf(l3 - mx);
  float inv = 1.f / (q0 + q1 + q2 + q3);
  qcsr[ep[e]] = make_float4(q0 * inv, q1 * inv, q2 * inv, q3 * inv);
}

// ---------------- fused FeaSt aggregation, 4 features per thread,
// optional fused graclus max-pool (values >= 0, pool_out pre-zeroed)
__global__ void k_attagg4(const int* __restrict__ rp, const int* __restrict__ ss,
                          const float4* __restrict__ qcsr, const float4* __restrict__ xW,
                          const float* __restrict__ c, const float4* __restrict__ b4,
                          float4* __restrict__ outp, int n, int fo4,
                          const int* __restrict__ pool_cl, int* __restrict__ pool_out) {
  int idx = blockIdx.x * 256 + threadIdx.x;
  if (idx >= n * fo4) return;
  int d = idx / fo4, og = idx - d * fo4;
  const int e0 = rp[d], e1 = rp[d + 1];
  float ax = 0.f, ay = 0.f, az = 0.f, aw = 0.f;
  for (int e = e0; e < e1; ++e) {
    int s = ss[e];
    float4 q = qcsr[e];
    const float4* m = xW + (size_t)s * 4 * fo4 + og;
    float4 m0 = m[0], m1 = m[fo4], m2 = m[2 * fo4], m3 = m[3 * fo4];
    ax += q.x * m0.x + q.y * m1.x + q.z * m2.x + q.w * m3.x;
    ay += q.x * m0.y + q.y * m1.y + q.z * m2.y + q.w * m3.y;
    az += q.x * m0.z + q.y * m1.z + q.z * m2.z + q.w * m3.z;
    aw += q.x * m0.w + q.y * m1.w + q.z * m2.w + q.w * m3.w;
  }
  // self-loop: q = softmax(c)
  {
    float c0 = c[0], c1 = c[1], c2 = c[2], c3 = c[3];
    float mx = fmaxf(fmaxf(c0, c1), fmaxf(c2, c3));
    float q0 = __expf(c0 - mx), q1 = __expf(c1 - mx);
    float q2 = __expf(c2 - mx), q3 = __expf(c3 - mx);
    float inv = 1.f / (q0 + q1 + q2 + q3);
    const float4* m = xW + (size_t)d * 4 * fo4 + og;
    float4 m0 = m[0], m1 = m[fo4], m2 = m[2 * fo4], m3 = m[3 * fo4];
    ax += (q0 * m0.x + q1 * m1.x + q2 * m2.x + q3 * m3.x) * inv;
    ay += (q0 * m0.y + q1 * m1.y + q2 * m2.y + q3 * m3.y) * inv;
    az += (q0 * m0.z + q1 * m1.z + q2 * m2.z + q3 * m3.z) * inv;
    aw += (q0 * m0.w + q1 * m1.w + q2 * m2.w + q3 * m3.w) * inv;
  }
  const float inv = 1.f / (float)(e1 - e0 + 1);
  const float4 bb = b4[og];
  float4 v;
  v.x = fmaxf(ax * inv + bb.x, 0.f);
  v.y = fmaxf(ay * inv + bb.y, 0.f);
  v.z = fmaxf(az * inv + bb.z, 0.f);
  v.w = fmaxf(aw * inv + bb.w, 0.f);
  outp[idx] = v;
  if (pool_cl) {
    int* po = pool_out + ((size_t)pool_cl[d] * fo4 + og) * 4;
    atomicMax(&po[0], __float_as_int(v.x));
    atomicMax(&po[1], __float_as_int(v.y));
    atomicMax(&po[2], __float_as_int(v.z));
    atomicMax(&po[3], __float_as_int(v.w));
  }
}

// ---------------- pack l2W [256][6890] fp32 -> bf16 B-fragments, + pad l2b/oW
// Bp[(t*8 + ks)*64 + lane][i] = l2W[ks*32 + (lane>>4)*8 + i][t*16 + (lane&15)]
__global__ void k_packB(const float* __restrict__ l2W, short8* __restrict__ Bp,
                        const float* __restrict__ l2b, const float* __restrict__ oW,
                        float* __restrict__ l2bp, float* __restrict__ oWp) {
  int idx = blockIdx.x * 256 + threadIdx.x;
  if (idx < JPAD) {
    l2bp[idx] = (idx < JREAL) ? l2b[idx] : 0.f;
    oWp[idx]  = (idx < JREAL) ? oW[idx]  : 0.f;
  }
  if (idx >= NTILE * 8 * 64) return;
  int l = idx & 63, ks = (idx >> 6) & 7, t = idx >> 9;
  int j = t * 16 + (l & 15);
  int kb = ks * 32 + ((l >> 4) << 3);
  short8 v;
#pragma unroll
  for (int i = 0; i < 8; ++i) {
    float f = (j < JREAL) ? l2W[(size_t)(kb + i) * JREAL + j] : 0.f;
    v[i] = (short)f2bf(f);
  }
  Bp[idx] = v;
}

// ---------------- h-build + l1 GEMM + relu + bf16 A-fragment pack
__global__ __launch_bounds__(256) void k_packh(
    const float* __restrict__ x1, const float* __restrict__ x5,
    const int* __restrict__ cl1, const float* __restrict__ l1W,
    const float* __restrict__ l1b, short8* __restrict__ Apack) {
  __shared__ float h1s[64][256];  // XOR-swizzled columns, 64 KB
  const int tid = threadIdx.x;
  const int row0 = blockIdx.x * 64;

  float wcol[32];
#pragma unroll
  for (int k = 0; k < 32; ++k) wcol[k] = l1W[k * 256 + tid];
  const float bt = l1b[tid];

  for (int r = 0; r < 64; ++r) {
    const int row = row0 + r;
    float s = bt;
    if (row < N1) {
      const float* a = x1 + (size_t)row * 16;
      const float* b = x5 + (size_t)cl1[row] * 16;
#pragma unroll
      for (int k = 0; k < 16; ++k) s = fmaf(a[k], wcol[k], s);
#pragma unroll
      for (int k = 0; k < 16; ++k) s = fmaf(b[k], wcol[16 + k], s);
    }
    h1s[r][tid ^ ((r & 7) << 3)] = fmaxf(s, 0.f);
  }
  __syncthreads();

#pragma unroll
  for (int j = 0; j < 8; ++j) {
    int s = j * 256 + tid;
    int l = s & 63, ks = (s >> 6) & 7, rb = s >> 9;
    int row = rb * 16 + (l & 15);
    int col0 = (ks * 32 + ((l >> 4) << 3)) ^ ((row & 7) << 3);
    const float* sp = &h1s[row][col0];
    short8 v;
#pragma unroll
    for (int i = 0; i < 8; ++i) v[i] = (short)f2bf(sp[i]);
    Apack[(size_t)blockIdx.x * 2048 + s] = v;
  }
}

// ---------------- l2 GEMM + relu + .oW epilogue (bf16 MFMA, 2-tile LDS stages)
__global__ __launch_bounds__(256, 2) void k_final2(
    const short8* __restrict__ Apack, const short8* __restrict__ Bp,
    const float* __restrict__ l2bp, const float* __restrict__ oWp,
    float* __restrict__ zbuf) {
  __shared__ short8 bufs[2][1024];   // 32 KB double buffer, 2 tiles per stage
  const int tid = threadIdx.x, wid = tid >> 6, l = tid & 63;
  const int rg = blockIdx.x >> 2, cg = blockIdx.x & 3;
  const int lm = l & 15, lh = l >> 4;

  // A fragments for this wave's 64 rows (coalesced, L2-resident)
  short8 af[4][8];
  {
    const short8* ap = Apack + (size_t)(rg * 4 + wid) * 2048 + l;
#pragma unroll
    for (int rb = 0; rb < 4; ++rb)
#pragma unroll
      for (int ks = 0; ks < 8; ++ks) af[rb][ks] = ap[rb * 512 + ks * 64];
  }

  const short8* bsrc = Bp + (size_t)cg * TPB * 512;
  // prolog: stage 0 -> buf0; stage 1 -> regs
  short8 n0 = bsrc[tid], n1 = bsrc[256 + tid], n2 = bsrc[512 + tid], n3 = bsrc[768 + tid];
  bufs[0][tid] = n0; bufs[0][256 + tid] = n1;
  bufs[0][512 + tid] = n2; bufs[0][768 + tid] = n3;
  {
    const short8* p = bsrc + 1024;
    n0 = p[tid]; n1 = p[256 + tid]; n2 = p[512 + tid]; n3 = p[768 + tid];
  }
  __syncthreads();

  float zp[4][4];
#pragma unroll
  for (int rb = 0; rb < 4; ++rb)
#pragma unroll
    for (int r = 0; r < 4; ++r) zp[rb][r] = 0.f;

  for (int st = 0; st < NSTG; ++st) {
    const int cur = st & 1;
    if (st + 1 < NSTG) {          // write-late: stage st+1 into other buffer
      bufs[cur ^ 1][tid] = n0; bufs[cur ^ 1][256 + tid] = n1;
      bufs[cur ^ 1][512 + tid] = n2; bufs[cur ^ 1][768 + tid] = n3;
    }
    if (st + 2 < NSTG) {          // issue-early: stage st+2 into regs
      const short8* p = bsrc + (st + 2) * 1024;
      n0 = p[tid]; n1 = p[256 + tid]; n2 = p[512 + tid]; n3 = p[768 + tid];
    }
#pragma unroll
    for (int half = 0; half < 2; ++half) {
      short8 bfr[8];
#pragma unroll
      for (int ks = 0; ks < 8; ++ks) bfr[ks] = bufs[cur][half * 512 + ks * 64 + l];

      f32x4 acc[4];
#pragma unroll
      for (int rb = 0; rb < 4; ++rb) acc[rb] = (f32x4){0.f, 0.f, 0.f, 0.f};
#pragma unroll
      for (int ks = 0; ks < 8; ++ks)
#pragma unroll
        for (int rb = 0; rb < 4; ++rb)
          acc[rb] = __builtin_amdgcn_mfma_f32_16x16x32_bf16(af[rb][ks], bfr[ks], acc[rb], 0, 0, 0);

      const int j = (cg * TPB + st * 2 + half) * 16 + lm;
      const float lb = l2bp[j];
      const float ow = oWp[j];
#pragma unroll
      for (int rb = 0; rb < 4; ++rb)
#pragma unroll
        for (int r = 0; r < 4; ++r)
          zp[rb][r] += fmaxf(acc[rb][r] + lb, 0.f) * ow;
    }
    __syncthreads();
  }

  // reduce over the 16 column-lanes
#pragma unroll
  for (int m = 1; m < 16; m <<= 1)
#pragma unroll
    for (int rb = 0; rb < 4; ++rb)
#pragma unroll
      for (int r = 0; r < 4; ++r)
        zp[rb][r] += __shfl_xor(zp[rb][r], m);

  if (lm == 0) {
    const int rbase = rg * 256 + wid * 64 + lh * 4;
#pragma unroll
    for (int rb = 0; rb < 4; ++rb)
#pragma unroll
      for (int r = 0; r < 4; ++r)
        atomicAdd(&zbuf[rbase + rb * 16 + r], zp[rb][r]);
  }
}

// ---------------- final sigmoid
__global__ void k_sigm(const float* __restrict__ zbuf, const float* __restrict__ ob,
                       float* __restrict__ out) {
  int i = blockIdx.x * 256 + threadIdx.x;
  if (i >= N1) return;
  out[i] = 1.f / (1.f + expf(-(zbuf[i] + ob[0])));
}

// ================= host side =================
static void run_conv(const float* xa, int fa, const float* xb, int fb, const int* gmap,
                     const int* ei, const int* ep, int E,
                     const int* rp, const int* ss, int n, int fo,
                     const float* W, const float* U, const float* c, const float* b,
                     float* outp, float* xW, float* xU, float4* qcsr,
                     const int* pool_cl, int* pool_out, hipStream_t stream) {
  int co = 4 * fo;
  k_matmulWU<<<(n * (co + 4) + 255) / 256, 256, 0, stream>>>(xa, fa, xb, fb, gmap,
                                                             W, U, xW, xU, n, co);
  k_edgeq<<<(E + 255) / 256, 256, 0, stream>>>(ei, ep, xU, c, qcsr, E);
  k_attagg4<<<(n * (fo / 4) + 255) / 256, 256, 0, stream>>>(
      rp, ss, qcsr, (const float4*)xW, c, (const float4*)b, (float4*)outp, n, fo / 4,
      pool_cl, pool_out);
}

extern "C" void kernel_launch(void* const* d_in, const int* in_sizes, int n_in,
                              void* d_out, int out_size, void* d_ws, size_t ws_size,
                              hipStream_t stream) {
  const float* x   = (const float*)d_in[0];
  const int* ei1   = (const int*)d_in[1];
  const int* ei2   = (const int*)d_in[2];
  const int* ei3   = (const int*)d_in[3];
  const int* cl1   = (const int*)d_in[4];
  const int* cl2   = (const int*)d_in[5];
  const float* cW1 = (const float*)d_in[6],  *cU1 = (const float*)d_in[7],
             * cc1 = (const float*)d_in[8],  *cb1 = (const float*)d_in[9];
  const float* cW2 = (const float*)d_in[10], *cU2 = (const float*)d_in[11],
             * cc2 = (const float*)d_in[12], *cb2 = (const float*)d_in[13];
  const float* cW3 = (const float*)d_in[14], *cU3 = (const float*)d_in[15],
             * cc3 = (const float*)d_in[16], *cb3 = (const float*)d_in[17];
  const float* cW4 = (const float*)d_in[18], *cU4 = (const float*)d_in[19],
             * cc4 = (const float*)d_in[20], *cb4 = (const float*)d_in[21];
  const float* cW5 = (const float*)d_in[22], *cU5 = (const float*)d_in[23],
             * cc5 = (const float*)d_in[24], *cb5 = (const float*)d_in[25];
  const float* l1W = (const float*)d_in[26], *l1b = (const float*)d_in[27];
  const float* l2W = (const float*)d_in[28], *l2b = (const float*)d_in[29];
  const float* oW  = (const float*)d_in[30], *ob  = (const float*)d_in[31];

  float* ws = (float*)d_ws;
  // ---- zeroed region: [0, 820192) floats ----
  float* x2p  = ws + 0;        // NN2*16 (pool1 out, needs zeros each call)
  float* x3p  = ws + 320000;   // NN3*32 (pool2 out, needs zeros each call)
  float* zbuf = ws + 640000;   // NROWP
  int*  deg1  = (int*)(ws + 680192);  // N1
  int*  cur1  = (int*)(ws + 720192);  // N1
  int*  deg2  = (int*)(ws + 760192);  // NN2
  int*  cur2  = (int*)(ws + 780192);  // NN2
  int*  deg3  = (int*)(ws + 800192);  // NN3
  int*  cur3  = (int*)(ws + 810192);  // NN3
  // ---- end zeroed region ----
  int*  rp1   = (int*)(ws + 820192);  // N1+1
  int*  rp2   = (int*)(ws + 860256);  // NN2+1
  int*  rp3   = (int*)(ws + 880320);  // NN3+1
  int*  ss1   = (int*)(ws + 890368);  // EE1
  int*  ss2   = (int*)(ws + 1530368); // EE2
  int*  ss3   = (int*)(ws + 1850368); // EE3
  int*  ep1   = (int*)(ws + 2010368); // EE1
  int*  ep2   = (int*)(ws + 2650368); // EE2
  int*  ep3   = (int*)(ws + 2970368); // EE3
  float* x1   = ws + 3130368;  // N1*16
  float* x2   = ws + 3770368;  // NN2*32
  float* x5   = ws + 4410368;  // NN2*16
  float* x3a  = ws + 4730368;  // NN3*64
  float* x3b  = ws + 5370368;  // NN3*32
  short8* Bp  = (short8*)(ws + 6970368);  // 432*8*64 frags
  float* l2bp = ws + 7855104;  // JPAD
  float* oWp  = ws + 7862016;  // JPAD
  float4* qcsr= (float4*)(ws + 7868928);  // EE1*4 floats
  float* xW   = ws + 10428928; // up to 2,560,000 (per conv)
  float* xU   = ws + 12988928; // up to 160,000
  // Apack aliases [qcsr ...): needs 5,144,576 floats; qcsr/xW/xU dead by then
  short8* Apack = (short8*)(ws + 7868928);
  // total = 13,148,928 floats = 52.6 MB

  hipMemsetAsync(ws, 0, 820192 * sizeof(float), stream);
  k_packB<<<(NTILE * 8 * 64 + 255) / 256, 256, 0, stream>>>(l2W, Bp, l2b, oW, l2bp, oWp);

  // CSR for the three edge sets (fused kernels)
  const int ET = EE1 + EE2 + EE3;
  k_hist3<<<(ET + 255) / 256, 256, 0, stream>>>(ei1 + EE1, ei2 + EE2, ei3 + EE3,
                                                deg1, deg2, deg3);
  k_scan3<<<3, 1024, 0, stream>>>(deg1, deg2, deg3, rp1, rp2, rp3);
  k_scatter3<<<(ET + 255) / 256, 256, 0, stream>>>(ei1, ei2, ei3, rp1, rp2, rp3,
                                                   cur1, cur2, cur3, ss1, ss2, ss3,
                                                   ep1, ep2, ep3);

  // conv1: x [N1,5] -> x1 [N1,16], fused pool1 -> x2p
  run_conv(x, 5, nullptr, 0, nullptr, ei1, ep1, EE1, rp1, ss1, N1, 16,
           cW1, cU1, cc1, cb1, x1, xW, xU, qcsr, cl1, (int*)x2p, stream);
  // conv2: x2p [NN2,16] -> x2 [NN2,32], fused pool2 -> x3p
  run_conv(x2p, 16, nullptr, 0, nullptr, ei2, ep2, EE2, rp2, ss2, NN2, 32,
           cW2, cU2, cc2, cb2, x2, xW, xU, qcsr, cl2, (int*)x3p, stream);
  // conv3: x3p [NN3,32] -> x3a [NN3,64]
  run_conv(x3p, 32, nullptr, 0, nullptr, ei3, ep3, EE3, rp3, ss3, NN3, 64,
           cW3, cU3, cc3, cb3, x3a, xW, xU, qcsr, nullptr, nullptr, stream);
  // conv4: x3a [NN3,64] -> x3b [NN3,32]
  run_conv(x3a, 64, nullptr, 0, nullptr, ei3, ep3, EE3, rp3, ss3, NN3, 32,
           cW4, cU4, cc4, cb4, x3b, xW, xU, qcsr, nullptr, nullptr, stream);
  // conv5: [x2 | x3b[cl2]] [NN2,64] -> x5 [NN2,16]  (concat fused into matmul)
  run_conv(x2, 32, x3b, 32, cl2, ei2, ep2, EE2, rp2, ss2, NN2, 16,
           cW5, cU5, cc5, cb5, x5, xW, xU, qcsr, nullptr, nullptr, stream);

  // MLP head: pack h1 A-frags, MFMA GEMM with fused relu.oW, sigmoid
  k_packh<<<NGRP, 256, 0, stream>>>(x1, x5, cl1, l1W, l1b, Apack);
  k_final2<<<(NROWP / 256) * CSPLIT, 256, 0, stream>>>(Apack, Bp, l2bp, oWp, zbuf);
  k_sigm<<<(N1 + 255) / 256, 256, 0, stream>>>(zbuf, ob, (float*)d_out);
}

// Round 6
// 660.964 us; speedup vs baseline: 7.2815x; 1.0834x over previous
//
#include <hip/hip_runtime.h>
#include <math.h>

#define N1  40000
#define NN2 20000
#define NN3 10000
#define EE1 640000
#define EE2 320000
#define EE3 160000
#define JPAD 6912   // 6890 padded to 432 tiles of 16
#define JREAL 6890
#define NTILE 432   // JPAD/16
#define CSPLIT 8
#define TPB (NTILE/CSPLIT)   // 54 tiles per col-group
#define NSTG (TPB/2)         // 27 two-tile stages
#define NROWP 40192          // 157*256 row pad
#define NGRP 628             // NROWP/64

typedef __attribute__((ext_vector_type(8))) short short8;
typedef __attribute__((ext_vector_type(4))) float f32x4;

__device__ inline unsigned short f2bf(float f) {
  unsigned u = __float_as_uint(f);
  u += 0x7FFF + ((u >> 16) & 1);   // round-to-nearest-even
  return (unsigned short)(u >> 16);
}

// ---------------- node-transform GEMMs with optional concat-gather input:
// row features = [Xa[row][0:fa] | Xb[map[row]][0:fb]]; xW = X@W [n,co], xU = X@U [n,4]
__global__ void k_matmulWU(const float* __restrict__ Xa, int fa,
                           const float* __restrict__ Xb, int fb,
                           const int* __restrict__ map,
                           const float* __restrict__ W, const float* __restrict__ U,
                           float* __restrict__ xW, float* __restrict__ xU,
                           int n, int co) {
  int ct = co + 4;
  int idx = blockIdx.x * 256 + threadIdx.x;
  if (idx >= n * ct) return;
  int row = idx / ct, col = idx - row * ct;
  const float* M;
  int stride;
  if (col < co) { M = W + col; stride = co; }
  else          { M = U + (col - co); stride = 4; }
  float s = 0.f;
  const float* ar = Xa + (size_t)row * fa;
  for (int k = 0; k < fa; ++k) s = fmaf(ar[k], M[(size_t)k * stride], s);
  if (Xb) {
    const float* br = Xb + (size_t)map[row] * fb;
    for (int k = 0; k < fb; ++k) s = fmaf(br[k], M[(size_t)(fa + k) * stride], s);
  }
  if (col < co) xW[(size_t)row * co + col] = s;
  else          xU[(size_t)row * 4 + (col - co)] = s;
}

// ---------------- CSR build (all 3 edge sets in one kernel): histogram
__global__ void k_hist3(const int* __restrict__ d1, const int* __restrict__ d2,
                        const int* __restrict__ d3, int* __restrict__ g1,
                        int* __restrict__ g2, int* __restrict__ g3) {
  int e = blockIdx.x * 256 + threadIdx.x;
  if (e < EE1) { atomicAdd(&g1[d1[e]], 1); return; }
  e -= EE1;
  if (e < EE2) { atomicAdd(&g2[d2[e]], 1); return; }
  e -= EE2;
  if (e < EE3) atomicAdd(&g3[d3[e]], 1);
}

// ---------------- CSR build: 3 concurrent single-block scans
__global__ __launch_bounds__(1024) void k_scan3(
    const int* __restrict__ g1, const int* __restrict__ g2, const int* __restrict__ g3,
    int* __restrict__ r1, int* __restrict__ r2, int* __restrict__ r3) {
  const int* deg; int* rp; int n;
  if (blockIdx.x == 0)      { deg = g1; rp = r1; n = N1; }
  else if (blockIdx.x == 1) { deg = g2; rp = r2; n = NN2; }
  else                      { deg = g3; rp = r3; n = NN3; }
  __shared__ int ssum[1024];
  const int tid = threadIdx.x;
  const int per = (n + 1023) >> 10;
  const int lo = tid * per, hi = min(lo + per, n);
  int s = 0;
  for (int i = lo; i < hi; ++i) s += deg[i];
  ssum[tid] = s;
  __syncthreads();
  for (int off = 1; off < 1024; off <<= 1) {
    int v = (tid >= off) ? ssum[tid - off] : 0;
    __syncthreads();
    ssum[tid] += v;
    __syncthreads();
  }
  int carry = (tid == 0) ? 0 : ssum[tid - 1];
  for (int i = lo; i < hi; ++i) { rp[i] = carry; carry += deg[i]; }
  if (tid == 1023) rp[n] = carry;
}

// ---------------- CSR build: scatter src ids into dst-sorted order
__global__ void k_scatter3(const int* __restrict__ ei1, const int* __restrict__ ei2,
                           const int* __restrict__ ei3, const int* __restrict__ r1,
                           const int* __restrict__ r2, const int* __restrict__ r3,
                           int* __restrict__ c1, int* __restrict__ c2, int* __restrict__ c3,
                           int* __restrict__ s1, int* __restrict__ s2, int* __restrict__ s3) {
  int e = blockIdx.x * 256 + threadIdx.x;
  const int* ei; const int* rp; int* cur; int* ss; int E;
  if (e < EE1) { ei = ei1; rp = r1; cur = c1; ss = s1; E = EE1; }
  else {
    e -= EE1;
    if (e < EE2) { ei = ei2; rp = r2; cur = c2; ss = s2; E = EE2; }
    else {
      e -= EE2;
      if (e >= EE3) return;
      ei = ei3; rp = r3; cur = c3; ss = s3; E = EE3;
    }
  }
  int d = ei[E + e];
  int pos = rp[d] + atomicAdd(&cur[d], 1);
  ss[pos] = ei[e];
}

// ---------------- fused FeaSt aggregation, 4 features per thread, q inline,
// optional fused graclus max-pool (values >= 0, pool_out pre-zeroed)
__global__ void k_attagg4(const int* __restrict__ rp, const int* __restrict__ ss,
                          const float* __restrict__ xU, const float4* __restrict__ xW,
                          const float* __restrict__ c, const float4* __restrict__ b4,
                          float4* __restrict__ outp, int n, int fo4,
                          const int* __restrict__ pool_cl, int* __restrict__ pool_out) {
  int idx = blockIdx.x * 256 + threadIdx.x;
  if (idx >= n * fo4) return;
  int d = idx / fo4, og = idx - d * fo4;
  const float c0 = c[0], c1 = c[1], c2 = c[2], c3 = c[3];
  const float4 xd = *(const float4*)&xU[(size_t)d * 4];
  const int e0 = rp[d], e1 = rp[d + 1];
  float ax = 0.f, ay = 0.f, az = 0.f, aw = 0.f;
  for (int e = e0; e < e1; ++e) {
    int s = ss[e];
    float4 xs = *(const float4*)&xU[(size_t)s * 4];
    float l0 = xs.x - xd.x + c0, l1 = xs.y - xd.y + c1;
    float l2 = xs.z - xd.z + c2, l3 = xs.w - xd.w + c3;
    float mx = fmaxf(fmaxf(l0, l1), fmaxf(l2, l3));
    float q0 = __expf(l0 - mx), q1 = __expf(l1 - mx);
    float q2 = __expf(l2 - mx), q3 = __expf(l3 - mx);
    float inv = 1.f / (q0 + q1 + q2 + q3);
    q0 *= inv; q1 *= inv; q2 *= inv; q3 *= inv;
    const float4* m = xW + (size_t)s * 4 * fo4 + og;
    float4 m0 = m[0], m1 = m[fo4], m2 = m[2 * fo4], m3 = m[3 * fo4];
    ax += q0 * m0.x + q1 * m1.x + q2 * m2.x + q3 * m3.x;
    ay += q0 * m0.y + q1 * m1.y + q2 * m2.y + q3 * m3.y;
    az += q0 * m0.z + q1 * m1.z + q2 * m2.z + q3 * m3.z;
    aw += q0 * m0.w + q1 * m1.w + q2 * m2.w + q3 * m3.w;
  }
  // self-loop: q = softmax(c)
  {
    float mx = fmaxf(fmaxf(c0, c1), fmaxf(c2, c3));
    float q0 = __expf(c0 - mx), q1 = __expf(c1 - mx);
    float q2 = __expf(c2 - mx), q3 = __expf(c3 - mx);
    float inv = 1.f / (q0 + q1 + q2 + q3);
    const float4* m = xW + (size_t)d * 4 * fo4 + og;
    float4 m0 = m[0], m1 = m[fo4], m2 = m[2 * fo4], m3 = m[3 * fo4];
    ax += (q0 * m0.x + q1 * m1.x + q2 * m2.x + q3 * m3.x) * inv;
    ay += (q0 * m0.y + q1 * m1.y + q2 * m2.y + q3 * m3.y) * inv;
    az += (q0 * m0.z + q1 * m1.z + q2 * m2.z + q3 * m3.z) * inv;
    aw += (q0 * m0.w + q1 * m1.w + q2 * m2.w + q3 * m3.w) * inv;
  }
  const float inv = 1.f / (float)(e1 - e0 + 1);
  const float4 bb = b4[og];
  float4 v;
  v.x = fmaxf(ax * inv + bb.x, 0.f);
  v.y = fmaxf(ay * inv + bb.y, 0.f);
  v.z = fmaxf(az * inv + bb.z, 0.f);
  v.w = fmaxf(aw * inv + bb.w, 0.f);
  outp[idx] = v;
  if (pool_cl) {
    int* po = pool_out + ((size_t)pool_cl[d] * fo4 + og) * 4;
    atomicMax(&po[0], __float_as_int(v.x));
    atomicMax(&po[1], __float_as_int(v.y));
    atomicMax(&po[2], __float_as_int(v.z));
    atomicMax(&po[3], __float_as_int(v.w));
  }
}

// ---------------- pack l2W [256][6890] fp32 -> bf16 B-fragments, + pad l2b/oW
// Bp[(t*8 + ks)*64 + lane][i] = l2W[ks*32 + (lane>>4)*8 + i][t*16 + (lane&15)]
__global__ void k_packB(const float* __restrict__ l2W, short8* __restrict__ Bp,
                        const float* __restrict__ l2b, const float* __restrict__ oW,
                        float* __restrict__ l2bp, float* __restrict__ oWp) {
  int idx = blockIdx.x * 256 + threadIdx.x;
  if (idx < JPAD) {
    l2bp[idx] = (idx < JREAL) ? l2b[idx] : 0.f;
    oWp[idx]  = (idx < JREAL) ? oW[idx]  : 0.f;
  }
  if (idx >= NTILE * 8 * 64) return;
  int l = idx & 63, ks = (idx >> 6) & 7, t = idx >> 9;
  int j = t * 16 + (l & 15);
  int kb = ks * 32 + ((l >> 4) << 3);
  short8 v;
#pragma unroll
  for (int i = 0; i < 8; ++i) {
    float f = (j < JREAL) ? l2W[(size_t)(kb + i) * JREAL + j] : 0.f;
    v[i] = (short)f2bf(f);
  }
  Bp[idx] = v;
}

// ---------------- h-build + l1 GEMM + relu + bf16 A-fragment pack
__global__ __launch_bounds__(256) void k_packh(
    const float* __restrict__ x1, const float* __restrict__ x5,
    const int* __restrict__ cl1, const float* __restrict__ l1W,
    const float* __restrict__ l1b, short8* __restrict__ Apack) {
  __shared__ float h1s[64][256];  // XOR-swizzled columns, 64 KB
  const int tid = threadIdx.x;
  const int row0 = blockIdx.x * 64;

  float wcol[32];
#pragma unroll
  for (int k = 0; k < 32; ++k) wcol[k] = l1W[k * 256 + tid];
  const float bt = l1b[tid];

  for (int r = 0; r < 64; ++r) {
    const int row = row0 + r;
    float s = bt;
    if (row < N1) {
      const float* a = x1 + (size_t)row * 16;
      const float* b = x5 + (size_t)cl1[row] * 16;
#pragma unroll
      for (int k = 0; k < 16; ++k) s = fmaf(a[k], wcol[k], s);
#pragma unroll
      for (int k = 0; k < 16; ++k) s = fmaf(b[k], wcol[16 + k], s);
    }
    h1s[r][tid ^ ((r & 7) << 3)] = fmaxf(s, 0.f);
  }
  __syncthreads();

#pragma unroll
  for (int j = 0; j < 8; ++j) {
    int s = j * 256 + tid;
    int l = s & 63, ks = (s >> 6) & 7, rb = s >> 9;
    int row = rb * 16 + (l & 15);
    int col0 = (ks * 32 + ((l >> 4) << 3)) ^ ((row & 7) << 3);
    const float* sp = &h1s[row][col0];
    short8 v;
#pragma unroll
    for (int i = 0; i < 8; ++i) v[i] = (short)f2bf(sp[i]);
    Apack[(size_t)blockIdx.x * 2048 + s] = v;
  }
}

// ---------------- l2 GEMM + relu + .oW epilogue (bf16 MFMA, raw-barrier pipeline)
// grid = 157 rg x 8 cg; counted-vmcnt reg staging, no vmcnt(0) drain at barriers
__global__ __launch_bounds__(256, 2) void k_final2(
    const short8* __restrict__ Apack, const short8* __restrict__ Bp,
    const float* __restrict__ l2bp, const float* __restrict__ oWp,
    float* __restrict__ zbuf) {
  __shared__ short8 bufs[2][1024];   // 32 KB double buffer, 2 tiles per stage
  const int tid = threadIdx.x, wid = tid >> 6, l = tid & 63;
  const int rg = blockIdx.x >> 3, cg = blockIdx.x & 7;
  const int lm = l & 15, lh = l >> 4;

  // A fragments for this wave's 64 rows (coalesced, L2-resident)
  short8 af[4][8];
  {
    const short8* ap = Apack + (size_t)(rg * 4 + wid) * 2048 + l;
#pragma unroll
    for (int rb = 0; rb < 4; ++rb)
#pragma unroll
      for (int ks = 0; ks < 8; ++ks) af[rb][ks] = ap[rb * 512 + ks * 64];
  }

  const short8* bsrc = Bp + (size_t)cg * TPB * 512;
  // prolog: stage 0 -> buf0; stage 1 -> regs
  short8 n0 = bsrc[tid], n1 = bsrc[256 + tid], n2 = bsrc[512 + tid], n3 = bsrc[768 + tid];
  bufs[0][tid] = n0; bufs[0][256 + tid] = n1;
  bufs[0][512 + tid] = n2; bufs[0][768 + tid] = n3;
  {
    const short8* p = bsrc + 1024;
    n0 = p[tid]; n1 = p[256 + tid]; n2 = p[512 + tid]; n3 = p[768 + tid];
  }
  asm volatile("s_waitcnt lgkmcnt(0)" ::: "memory");
  __builtin_amdgcn_s_barrier();
  asm volatile("" ::: "memory");

  float zp[4][4];
#pragma unroll
  for (int rb = 0; rb < 4; ++rb)
#pragma unroll
    for (int r = 0; r < 4; ++r) zp[rb][r] = 0.f;

  for (int st = 0; st < NSTG; ++st) {
    const int cur = st & 1;
    if (st + 1 < NSTG) {          // write-late: stage st+1 into other buffer
      bufs[cur ^ 1][tid] = n0; bufs[cur ^ 1][256 + tid] = n1;
      bufs[cur ^ 1][512 + tid] = n2; bufs[cur ^ 1][768 + tid] = n3;
    }
    if (st + 2 < NSTG) {          // issue-early: stage st+2 into regs
      const short8* p = bsrc + (st + 2) * 1024;
      n0 = p[tid]; n1 = p[256 + tid]; n2 = p[512 + tid]; n3 = p[768 + tid];
    }
#pragma unroll
    for (int half = 0; half < 2; ++half) {
      short8 bfr[8];
#pragma unroll
      for (int ks = 0; ks < 8; ++ks) bfr[ks] = bufs[cur][half * 512 + ks * 64 + l];

      f32x4 acc[4];
#pragma unroll
      for (int rb = 0; rb < 4; ++rb) acc[rb] = (f32x4){0.f, 0.f, 0.f, 0.f};
      __builtin_amdgcn_s_setprio(1);
#pragma unroll
      for (int ks = 0; ks < 8; ++ks)
#pragma unroll
        for (int rb = 0; rb < 4; ++rb)
          acc[rb] = __builtin_amdgcn_mfma_f32_16x16x32_bf16(af[rb][ks], bfr[ks], acc[rb], 0, 0, 0);
      __builtin_amdgcn_s_setprio(0);

      const int j = (cg * TPB + st * 2 + half) * 16 + lm;
      const float lb = l2bp[j];
      const float ow = oWp[j];
#pragma unroll
      for (int rb = 0; rb < 4; ++rb)
#pragma unroll
        for (int r = 0; r < 4; ++r)
          zp[rb][r] += fmaxf(acc[rb][r] + lb, 0.f) * ow;
    }
    asm volatile("s_waitcnt lgkmcnt(0)" ::: "memory");
    __builtin_amdgcn_s_barrier();
    asm volatile("" ::: "memory");
  }

  // reduce over the 16 column-lanes
#pragma unroll
  for (int m = 1; m < 16; m <<= 1)
#pragma unroll
    for (int rb = 0; rb < 4; ++rb)
#pragma unroll
      for (int r = 0; r < 4; ++r)
        zp[rb][r] += __shfl_xor(zp[rb][r], m);

  if (lm == 0) {
    const int rbase = rg * 256 + wid * 64 + lh * 4;
#pragma unroll
    for (int rb = 0; rb < 4; ++rb)
#pragma unroll
      for (int r = 0; r < 4; ++r)
        atomicAdd(&zbuf[rbase + rb * 16 + r], zp[rb][r]);
  }
}

// ---------------- final sigmoid
__global__ void k_sigm(const float* __restrict__ zbuf, const float* __restrict__ ob,
                       float* __restrict__ out) {
  int i = blockIdx.x * 256 + threadIdx.x;
  if (i >= N1) return;
  out[i] = 1.f / (1.f + expf(-(zbuf[i] + ob[0])));
}

// ================= host side =================
static void run_conv(const float* xa, int fa, const float* xb, int fb, const int* gmap,
                     const int* rp, const int* ss, int n, int fo,
                     const float* W, const float* U, const float* c, const float* b,
                     float* outp, float* xW, float* xU,
                     const int* pool_cl, int* pool_out, hipStream_t stream) {
  int co = 4 * fo;
  k_matmulWU<<<(n * (co + 4) + 255) / 256, 256, 0, stream>>>(xa, fa, xb, fb, gmap,
                                                             W, U, xW, xU, n, co);
  k_attagg4<<<(n * (fo / 4) + 255) / 256, 256, 0, stream>>>(
      rp, ss, xU, (const float4*)xW, c, (const float4*)b, (float4*)outp, n, fo / 4,
      pool_cl, pool_out);
}

extern "C" void kernel_launch(void* const* d_in, const int* in_sizes, int n_in,
                              void* d_out, int out_size, void* d_ws, size_t ws_size,
                              hipStream_t stream) {
  const float* x   = (const float*)d_in[0];
  const int* ei1   = (const int*)d_in[1];
  const int* ei2   = (const int*)d_in[2];
  const int* ei3   = (const int*)d_in[3];
  const int* cl1   = (const int*)d_in[4];
  const int* cl2   = (const int*)d_in[5];
  const float* cW1 = (const float*)d_in[6],  *cU1 = (const float*)d_in[7],
             * cc1 = (const float*)d_in[8],  *cb1 = (const float*)d_in[9];
  const float* cW2 = (const float*)d_in[10], *cU2 = (const float*)d_in[11],
             * cc2 = (const float*)d_in[12], *cb2 = (const float*)d_in[13];
  const float* cW3 = (const float*)d_in[14], *cU3 = (const float*)d_in[15],
             * cc3 = (const float*)d_in[16], *cb3 = (const float*)d_in[17];
  const float* cW4 = (const float*)d_in[18], *cU4 = (const float*)d_in[19],
             * cc4 = (const float*)d_in[20], *cb4 = (const float*)d_in[21];
  const float* cW5 = (const float*)d_in[22], *cU5 = (const float*)d_in[23],
             * cc5 = (const float*)d_in[24], *cb5 = (const float*)d_in[25];
  const float* l1W = (const float*)d_in[26], *l1b = (const float*)d_in[27];
  const float* l2W = (const float*)d_in[28], *l2b = (const float*)d_in[29];
  const float* oW  = (const float*)d_in[30], *ob  = (const float*)d_in[31];

  float* ws = (float*)d_ws;
  // ---- zeroed region: [0, 820192) floats ----
  float* x2p  = ws + 0;        // NN2*16 (pool1 out, needs zeros each call)
  float* x3p  = ws + 320000;   // NN3*32 (pool2 out, needs zeros each call)
  float* zbuf = ws + 640000;   // NROWP
  int*  deg1  = (int*)(ws + 680192);  // N1
  int*  cur1  = (int*)(ws + 720192);  // N1
  int*  deg2  = (int*)(ws + 760192);  // NN2
  int*  cur2  = (int*)(ws + 780192);  // NN2
  int*  deg3  = (int*)(ws + 800192);  // NN3
  int*  cur3  = (int*)(ws + 810192);  // NN3
  // ---- end zeroed region ----
  int*  rp1   = (int*)(ws + 820192);  // N1+1
  int*  rp2   = (int*)(ws + 860256);  // NN2+1
  int*  rp3   = (int*)(ws + 880320);  // NN3+1
  int*  ss1   = (int*)(ws + 890368);  // EE1
  int*  ss2   = (int*)(ws + 1530368); // EE2
  int*  ss3   = (int*)(ws + 1850368); // EE3
  float* x1   = ws + 3130368;  // N1*16
  float* x2   = ws + 3770368;  // NN2*32
  float* x5   = ws + 4410368;  // NN2*16
  float* x3a  = ws + 4730368;  // NN3*64
  float* x3b  = ws + 5370368;  // NN3*32
  short8* Bp  = (short8*)(ws + 6970368);  // 432*8*64 frags
  float* l2bp = ws + 7855104;  // JPAD
  float* oWp  = ws + 7862016;  // JPAD
  float* xW   = ws + 10428928; // up to 2,560,000 (per conv)
  float* xU   = ws + 12988928; // up to 160,000
  // Apack aliases [7868928 ...): needs 5,144,576 floats; xW/xU dead after conv5
  short8* Apack = (short8*)(ws + 7868928);
  // total = 13,148,928 floats = 52.6 MB

  hipMemsetAsync(ws, 0, 820192 * sizeof(float), stream);
  k_packB<<<(NTILE * 8 * 64 + 255) / 256, 256, 0, stream>>>(l2W, Bp, l2b, oW, l2bp, oWp);

  // CSR for the three edge sets (fused kernels)
  const int ET = EE1 + EE2 + EE3;
  k_hist3<<<(ET + 255) / 256, 256, 0, stream>>>(ei1 + EE1, ei2 + EE2, ei3 + EE3,
                                                deg1, deg2, deg3);
  k_scan3<<<3, 1024, 0, stream>>>(deg1, deg2, deg3, rp1, rp2, rp3);
  k_scatter3<<<(ET + 255) / 256, 256, 0, stream>>>(ei1, ei2, ei3, rp1, rp2, rp3,
                                                   cur1, cur2, cur3, ss1, ss2, ss3);

  // conv1: x [N1,5] -> x1 [N1,16], fused pool1 -> x2p
  run_conv(x, 5, nullptr, 0, nullptr, rp1, ss1, N1, 16,
           cW1, cU1, cc1, cb1, x1, xW, xU, cl1, (int*)x2p, stream);
  // conv2: x2p [NN2,16] -> x2 [NN2,32], fused pool2 -> x3p
  run_conv(x2p, 16, nullptr, 0, nullptr, rp2, ss2, NN2, 32,
           cW2, cU2, cc2, cb2, x2, xW, xU, cl2, (int*)x3p, stream);
  // conv3: x3p [NN3,32] -> x3a [NN3,64]
  run_conv(x3p, 32, nullptr, 0, nullptr, rp3, ss3, NN3, 64,
           cW3, cU3, cc3, cb3, x3a, xW, xU, nullptr, nullptr, stream);
  // conv4: x3a [NN3,64] -> x3b [NN3,32]
  run_conv(x3a, 64, nullptr, 0, nullptr, rp3, ss3, NN3, 32,
           cW4, cU4, cc4, cb4, x3b, xW, xU, nullptr, nullptr, stream);
  // conv5: [x2 | x3b[cl2]] [NN2,64] -> x5 [NN2,16]  (concat fused into matmul)
  run_conv(x2, 32, x3b, 32, cl2, rp2, ss2, NN2, 16,
           cW5, cU5, cc5, cb5, x5, xW, xU, nullptr, nullptr, stream);

  // MLP head: pack h1 A-frags, MFMA GEMM with fused relu.oW, sigmoid
  k_packh<<<NGRP, 256, 0, stream>>>(x1, x5, cl1, l1W, l1b, Apack);
  k_final2<<<(NROWP / 256) * CSPLIT, 256, 0, stream>>>(Apack, Bp, l2bp, oWp, zbuf);
  k_sigm<<<(N1 + 255) / 256, 256, 0, stream>>>(zbuf, ob, (float*)d_out);
}